// Round 4
// baseline (813.537 us; speedup 1.0000x reference)
//
#include <hip/hip_runtime.h>
#include <stdint.h>

// Problem constants
#define AA 144          // ATOM*ATOM
#define LAM 0.1f

// ---- workspace layout (float offsets) ----
#define OFS_SC    0            // 64 scalars: [0..15]=traces, [16]=scX, [17]=scA
#define OFS_AF1   64           // 128*144 row-normalized zero-mean atoms
#define OFS_AF1T  18496        // 144*128 transposed
#define OFS_G     36928        // 128*128 gram
#define OFS_S0    53312        // squaring ping
#define OFS_S1    69696        // squaring pong
#define OFS_X     86080        // final FISTA gram
#define OFS_AN    102464       // atoms_n (n-major)
#define OFS_AT    120896       // atoms_n (k-major)
#define OFS_PM    139328       // 32768 patch means
#define OFS_GOAL  172096       // 45056 goal (f32)
#define OFS_Q     217152       // 32768*128
#define OFS_CF    4411456      // 32768*128
#define OFS_PRED  8605760      // 32768*144
// total = 13,324,352 floats = ~50.9 MB

__device__ __forceinline__ float proxf(float u) {
    float a = fmaxf(fabsf(u) - LAM, 0.0f);
    return copysignf(a, u);
}

// ---- setup: per-atom zero-mean unit-norm rows -> Af1, Af1T; init trace slots ----
__global__ __launch_bounds__(256) void k_norm(const float* atoms, float* ws) {
    int t = threadIdx.x;
    if (t >= 128 && t < 144) ws[OFS_SC + (t - 128)] = (t == 128) ? 128.0f : 0.0f;
    if (t < 128) {
        const float* ap = atoms + t * AA;
        float s = 0.f;
        for (int k = 0; k < AA; ++k) s += ap[k];
        float mean = s * (1.0f / 144.0f);
        float ss = 0.f;
        for (int k = 0; k < AA; ++k) { float a = ap[k] - mean; ss = fmaf(a, a, ss); }
        float rn = 1.0f / sqrtf(ss);
        for (int k = 0; k < AA; ++k) {
            float a = (ap[k] - mean) * rn;
            ws[OFS_AF1  + t * AA + k] = a;
            ws[OFS_AF1T + k * 128 + t] = a;
        }
    }
}

// ---- G = Af1 @ Af1^T ----
__global__ __launch_bounds__(256) void k_gram(float* ws) {
    __shared__ float Ai[8 * AA];
    int t = threadIdx.x;
    int i0 = blockIdx.x * 8;
    for (int e = t; e < 8 * AA; e += 256) Ai[e] = ws[OFS_AF1 + i0 * AA + e];
    __syncthreads();
    int ti = t >> 5, tj = t & 31;
    float a0 = 0, a1 = 0, a2 = 0, a3 = 0;
    for (int k = 0; k < AA; ++k) {
        float a = Ai[ti * AA + k];
        float4 bv = *(const float4*)&ws[OFS_AF1T + k * 128 + tj * 4];
        a0 = fmaf(a, bv.x, a0); a1 = fmaf(a, bv.y, a1);
        a2 = fmaf(a, bv.z, a2); a3 = fmaf(a, bv.w, a3);
    }
    *(float4*)&ws[OFS_G + (i0 + ti) * 128 + tj * 4] = make_float4(a0, a1, a2, a3);
}

// ---- OUT = (IN/trace_in)^2 ; accumulate trace(OUT). PSD => traces in [1/128,1]. ----
__global__ __launch_bounds__(256) void k_square(const float* IN, float* OUT,
                                                const float* tr_in, float* tr_out) {
    __shared__ float R[256];
    int t = threadIdx.x;
    int r0 = blockIdx.x * 2;
    R[t] = IN[r0 * 128 + t];
    __syncthreads();
    float s = tr_in[0];
    float inv2 = 1.0f / (s * s);
    int r = t >> 7, c = t & 127;
    float acc = 0.f;
    const float* Rr = &R[r * 128];
    for (int k = 0; k < 128; ++k) acc = fmaf(Rr[k], IN[k * 128 + c], acc);
    acc *= inv2;
    OUT[(r0 + r) * 128 + c] = acc;
    if (c == r0 + r) atomicAdd(tr_out, acc);
}

// ---- Rayleigh quotient on P ~ G^256: v = P*ones; lam = v'Gv / v'v ----
__global__ __launch_bounds__(128) void k_rayleigh(const float* P, const float* G,
                                                  const float* mu_p, float* sc) {
    __shared__ float v[128];
    __shared__ float red[256];
    int t = threadIdx.x;
    float s = 0.f;
    for (int k = 0; k < 128; ++k) s += P[t * 128 + k];
    v[t] = s;
    __syncthreads();
    float w = 0.f;
    for (int k = 0; k < 128; ++k) w = fmaf(G[t * 128 + k], v[k], w);
    red[t] = v[t] * w;
    red[128 + t] = v[t] * v[t];
    __syncthreads();
    for (int off = 64; off > 0; off >>= 1) {
        if (t < off) { red[t] += red[t + off]; red[128 + t] += red[128 + t + off]; }
        __syncthreads();
    }
    if (t == 0) {
        float lam = red[0] / red[128];               // sigma^2 = lammax(G)
        float mu = fmaxf(mu_p[0], 0.0f);
        sc[16] = 1.0f / (lam * mu);                  // X scale: G/(sigma^2*mu)
        sc[17] = 1.0f / (sqrtf(lam) * sqrtf(mu));    // atom scale: 1/(sigma*sqrt(mu))
    }
}

// ---- X = G*scX ; atoms_n = Af1*scA (both layouts) ----
__global__ __launch_bounds__(256) void k_finalize(float* ws) {
    int idx = blockIdx.x * 256 + threadIdx.x;
    float scX = ws[OFS_SC + 16], scA = ws[OFS_SC + 17];
    if (idx < 16384) {
        ws[OFS_X + idx] = ws[OFS_G + idx] * scX;
    } else {
        int e = idx - 16384;
        if (e < 18432) {
            int n = e / AA, k = e - n * AA;
            float a = ws[OFS_AF1 + e] * scA;
            ws[OFS_AN + e] = a;
            ws[OFS_AT + k * 128 + n] = a;
        }
    }
}

// ---- goal init: copy y -> GOAL ----
__global__ __launch_bounds__(256) void k_goalinit(const float* y, float* goal) {
    int idx = blockIdx.x * 256 + threadIdx.x;
    if (idx < 45000) goal[idx] = y[idx];
}

// ---- patch means of y (fixed across unrolls) ----
__global__ __launch_bounds__(256) void k_patchmean(const float* y, float* pm) {
    int p = blockIdx.x * 256 + threadIdx.x;     // 32768
    int b = p >> 12, pi = (p >> 6) & 63, pj = p & 63;
    const float* yb = y + b * 5625;
    float s = 0.f;
    for (int di = 0; di < 12; ++di) {
        const float* row = yb + (pi + di) * 75 + pj;
        for (int dj = 0; dj < 12; ++dj) s += row[dj];
    }
    pm[p] = s * (1.0f / 144.0f);
}

// ---- q[p][n] = valid-corr(goal, atoms_n); block = (pi, b), 64 pj x 128 n ----
__global__ __launch_bounds__(256) void k_q(const float* goal, const float* At, float* q) {
    __shared__ float Ats[AA * 128];
    __shared__ float gls[12 * 76];
    int t = threadIdx.x;
    int pi = blockIdx.x, b = blockIdx.y;
    for (int it = 0; it < 18; ++it)
        ((float4*)Ats)[t + it * 256] = ((const float4*)At)[t + it * 256];
    for (int e = t; e < 912; e += 256) {
        int r = e / 76, cc = e - r * 76;
        float v = 0.f;
        if (cc < 75) v = goal[b * 5625 + (pi + r) * 75 + cc];
        gls[e] = v;
    }
    __syncthreads();
    int tn = t & 31, tp = t >> 5;   // n0 = 4*tn, pj = 8*tp + r
    float acc[8][4] = {};
    for (int di = 0; di < 12; ++di) {
        #pragma unroll
        for (int dj = 0; dj < 12; ++dj) {
            float a[4];
            *(float4*)a = *(const float4*)&Ats[(di * 12 + dj) * 128 + tn * 4];
            const float* g = &gls[di * 76 + tp * 8 + dj];
            #pragma unroll
            for (int r = 0; r < 8; ++r) {
                float gv = g[r];
                acc[r][0] = fmaf(gv, a[0], acc[r][0]);
                acc[r][1] = fmaf(gv, a[1], acc[r][1]);
                acc[r][2] = fmaf(gv, a[2], acc[r][2]);
                acc[r][3] = fmaf(gv, a[3], acc[r][3]);
            }
        }
    }
    int pbase = (b * 64 + pi) * 64 + tp * 8;
    #pragma unroll
    for (int r = 0; r < 8; ++r)
        *(float4*)&q[(pbase + r) * 128 + tn * 4] = *(float4*)acc[r];
}

// ---- fused FISTA (15 iters) + 1 differentiable step. 32 patches/block.
//      LDS: X 64KB + Z 16KB = 80KB -> 2 blocks/CU on gfx950 (160KB). ----
__global__ __launch_bounds__(256) void k_fista(const float* Xg, const float* qg, float* cfg,
                                               const float* mu_p, int first) {
    __shared__ float Xs[16384];
    __shared__ float Zs[4096];
    int t = threadIdx.x;
    int tn = t & 31, tp = t >> 5;
    int n0 = tn * 4, tp4 = tp * 4;
    int p0 = blockIdx.x * 32;
    for (int it = 0; it < 16; ++it)
        ((float4*)Xs)[t + it * 256] = ((const float4*)Xg)[t + it * 256];
    float mu = fmaxf(mu_p[0], 0.0f);
    float qr[4][4], cr[4][4], cfv[4][4];
    #pragma unroll
    for (int i = 0; i < 4; ++i) {
        int p = p0 + tp4 + i;
        *(float4*)qr[i] = *(const float4*)&qg[p * 128 + n0];
        if (first) { cr[i][0] = cr[i][1] = cr[i][2] = cr[i][3] = 0.f; }
        else       { *(float4*)cr[i] = *(const float4*)&cfg[p * 128 + n0]; }
        *(float4*)&Zs[(tp4 + i) * 128 + n0] = *(float4*)cr[i];   // z0 = c0
    }
    float tmom = 1.0f;
    #pragma unroll 1
    for (int it = 0; it < 16; ++it) {
        __syncthreads();
        float acc[4][4] = {};
        #pragma unroll 4
        for (int k4 = 0; k4 < 32; ++k4) {
            float zr[4][4], xr[4][4];
            #pragma unroll
            for (int i = 0; i < 4; ++i)
                *(float4*)zr[i] = *(const float4*)&Zs[(tp4 + i) * 128 + k4 * 4];
            #pragma unroll
            for (int kk = 0; kk < 4; ++kk)
                *(float4*)xr[kk] = *(const float4*)&Xs[(k4 * 4 + kk) * 128 + n0];
            #pragma unroll
            for (int i = 0; i < 4; ++i)
                #pragma unroll
                for (int kk = 0; kk < 4; ++kk) {
                    acc[i][0] = fmaf(zr[i][kk], xr[kk][0], acc[i][0]);
                    acc[i][1] = fmaf(zr[i][kk], xr[kk][1], acc[i][1]);
                    acc[i][2] = fmaf(zr[i][kk], xr[kk][2], acc[i][2]);
                    acc[i][3] = fmaf(zr[i][kk], xr[kk][3], acc[i][3]);
                }
        }
        if (it < 15) {
            float tnn = 0.5f * (1.0f + sqrtf(1.0f + 4.0f * tmom * tmom));
            float fm = (tmom - 1.0f) / tnn;
            tmom = tnn;
            float wv[4][4];
            #pragma unroll
            for (int i = 0; i < 4; ++i) {
                float zo[4];
                *(float4*)zo = *(const float4*)&Zs[(tp4 + i) * 128 + n0];
                #pragma unroll
                for (int j = 0; j < 4; ++j) {
                    float cn = proxf(zo[j] + mu * (qr[i][j] - acc[i][j]));
                    float zn = cn + fm * (cn - cr[i][j]);
                    cr[i][j] = cn;
                    // last FISTA iter: z15 never used; stage c15 for the final diff step
                    wv[i][j] = (it == 14) ? cn : zn;
                }
            }
            __syncthreads();
            #pragma unroll
            for (int i = 0; i < 4; ++i)
                *(float4*)&Zs[(tp4 + i) * 128 + n0] = *(float4*)wv[i];
        } else {
            #pragma unroll
            for (int i = 0; i < 4; ++i)
                #pragma unroll
                for (int j = 0; j < 4; ++j)
                    cfv[i][j] = proxf(cr[i][j] + mu * (qr[i][j] - acc[i][j]));
        }
    }
    #pragma unroll
    for (int i = 0; i < 4; ++i)
        *(float4*)&cfg[(p0 + tp4 + i) * 128 + n0] = *(float4*)cfv[i];
}

// ---- pred[p][144] = cf[p,:] @ atoms_n + patch_mean[p]; 64 patches/block ----
__global__ __launch_bounds__(256) void k_pred(const float* AN, const float* cfg,
                                              const float* pm, float* pred) {
    __shared__ float As[128 * AA];
    __shared__ float Cs[64 * 129];
    int t = threadIdx.x;
    int p0 = blockIdx.x * 64;
    for (int it = 0; it < 18; ++it)
        ((float4*)As)[t + it * 256] = ((const float4*)AN)[t + it * 256];
    for (int it = 0; it < 8; ++it) {
        int i4 = t + it * 256;                 // < 2048
        int pr = i4 >> 5, nc = (i4 & 31) * 4;
        float v[4];
        *(float4*)v = *(const float4*)&cfg[(p0 + pr) * 128 + nc];
        float* d = &Cs[pr * 129 + nc];
        d[0] = v[0]; d[1] = v[1]; d[2] = v[2]; d[3] = v[3];
    }
    __syncthreads();
    int tj = t & 15, tp = t >> 4;
    int j0 = tj * 9;
    float acc[4][9] = {};
    for (int n = 0; n < 128; ++n) {
        float cv[4];
        #pragma unroll
        for (int i = 0; i < 4; ++i) cv[i] = Cs[(tp * 4 + i) * 129 + n];
        #pragma unroll
        for (int jj = 0; jj < 9; ++jj) {
            float av = As[n * AA + j0 + jj];
            #pragma unroll
            for (int i = 0; i < 4; ++i) acc[i][jj] = fmaf(cv[i], av, acc[i][jj]);
        }
    }
    #pragma unroll
    for (int i = 0; i < 4; ++i) {
        int p = p0 + tp * 4 + i;
        float pmv = pm[p];
        #pragma unroll
        for (int jj = 0; jj < 9; ++jj) pred[p * AA + j0 + jj] = acc[i][jj] + pmv;
    }
}

// ---- fold (overlap-add gather) + goal update; f32 output on final unroll ----
__global__ __launch_bounds__(256) void k_fold(const float* y, const float* beta_p,
                                              const float* pred, float* goal,
                                              float* out, int write_out) {
    int idx = blockIdx.x * 256 + threadIdx.x;
    if (idx >= 5625) return;
    int b = blockIdx.y;
    int i = idx / 75, j = idx - i * 75;
    float S = 0.f;
    for (int di = 0; di < 12; ++di) {
        int pi = i - di;
        if ((unsigned)pi >= 64u) continue;
        int base = (b << 12) + (pi << 6);
        for (int dj = 0; dj < 12; ++dj) {
            int pj = j - dj;
            if ((unsigned)pj >= 64u) continue;
            S += pred[(base + pj) * AA + di * 12 + dj];
        }
    }
    int ci = min(i, 11) - max(i - 63, 0) + 1;
    int cj = min(j, 11) - max(j - 63, 0) + 1;
    float beta = fmaxf(beta_p[0], 0.0f);
    float yv = y[b * 5625 + idx];
    float g = (yv + beta * S) / (1.0f + beta * (float)(ci * cj));
    goal[b * 5625 + idx] = g;
    if (write_out) out[b * 5625 + idx] = g;     // f32 output (reference output dtype)
}

extern "C" void kernel_launch(void* const* d_in, const int* in_sizes, int n_in,
                              void* d_out, int out_size, void* d_ws, size_t ws_size,
                              hipStream_t stream) {
    const float* y     = (const float*)d_in[0];
    const float* atoms = (const float*)d_in[1];
    const float* beta  = (const float*)d_in[2];
    const float* mu    = (const float*)d_in[3];
    float* out = (float*)d_out;
    float* ws = (float*)d_ws;

    k_norm<<<1, 256, 0, stream>>>(atoms, ws);
    k_gram<<<16, 256, 0, stream>>>(ws);
    for (int j = 0; j < 8; ++j) {           // G^(2^8) via trace-normalized squaring
        const float* IN = ws + (j == 0 ? OFS_G : ((j & 1) ? OFS_S0 : OFS_S1));
        float* OUT = ws + ((j & 1) ? OFS_S1 : OFS_S0);
        k_square<<<64, 256, 0, stream>>>(IN, OUT, ws + OFS_SC + j, ws + OFS_SC + j + 1);
    }
    k_rayleigh<<<1, 128, 0, stream>>>(ws + OFS_S1, ws + OFS_G, mu, ws + OFS_SC);
    k_finalize<<<136, 256, 0, stream>>>(ws);
    k_goalinit<<<176, 256, 0, stream>>>(y, ws + OFS_GOAL);
    k_patchmean<<<128, 256, 0, stream>>>(y, ws + OFS_PM);

    for (int u = 0; u < 2; ++u) {
        k_q<<<dim3(64, 8), 256, 0, stream>>>(ws + OFS_GOAL, ws + OFS_AT, ws + OFS_Q);
        k_fista<<<1024, 256, 0, stream>>>(ws + OFS_X, ws + OFS_Q, ws + OFS_CF,
                                          mu, u == 0 ? 1 : 0);
        k_pred<<<512, 256, 0, stream>>>(ws + OFS_AN, ws + OFS_CF, ws + OFS_PM, ws + OFS_PRED);
        k_fold<<<dim3(22, 8), 256, 0, stream>>>(y, beta, ws + OFS_PRED,
                                                ws + OFS_GOAL, out, u == 1 ? 1 : 0);
    }
}

// Round 5
// 445.046 us; speedup vs baseline: 1.8280x; 1.8280x over previous
//
#include <hip/hip_runtime.h>
#include <stdint.h>

// Problem constants
#define AA 144          // ATOM*ATOM
#define LAM 0.1f

// ---- workspace layout (float offsets) ----
#define OFS_SC    0            // 64 scalars: [0..15]=traces, [16]=scX, [17]=scA
#define OFS_AF1   64           // 128*144 row-normalized zero-mean atoms
#define OFS_AF1T  18496        // 144*128 transposed
#define OFS_G     36928        // 128*128 gram
#define OFS_S0    53312        // squaring ping
#define OFS_S1    69696        // squaring pong
#define OFS_X     86080        // final FISTA gram
#define OFS_AN    102464       // atoms_n (n-major)
#define OFS_AT    120896       // atoms_n (k-major)
#define OFS_PM    139328       // 32768 patch means
#define OFS_GOAL  172096       // 45056 goal (f32)
#define OFS_Q     217152       // 32768*128
#define OFS_CF    4411456      // 32768*128
#define OFS_PRED  8605760      // 32768*144
// total = 13,324,352 floats = ~50.9 MB

typedef __attribute__((ext_vector_type(8))) short short8_t;
typedef __attribute__((ext_vector_type(4))) float f32x4;

__device__ __forceinline__ float proxf(float u) {
    float a = fmaxf(fabsf(u) - LAM, 0.0f);
    return copysignf(a, u);
}
__device__ __forceinline__ unsigned short f2bf(float f) {
    union { float f; uint32_t u; } x; x.f = f;
    uint32_t u = x.u;
    return (unsigned short)((u + 0x7FFFu + ((u >> 16) & 1u)) >> 16);
}

// ---- setup: per-atom zero-mean unit-norm rows -> Af1, Af1T; init trace slots ----
__global__ __launch_bounds__(256) void k_norm(const float* atoms, float* ws) {
    int t = threadIdx.x;
    if (t >= 128 && t < 144) ws[OFS_SC + (t - 128)] = (t == 128) ? 128.0f : 0.0f;
    if (t < 128) {
        const float* ap = atoms + t * AA;
        float s = 0.f;
        for (int k = 0; k < AA; ++k) s += ap[k];
        float mean = s * (1.0f / 144.0f);
        float ss = 0.f;
        for (int k = 0; k < AA; ++k) { float a = ap[k] - mean; ss = fmaf(a, a, ss); }
        float rn = 1.0f / sqrtf(ss);
        for (int k = 0; k < AA; ++k) {
            float a = (ap[k] - mean) * rn;
            ws[OFS_AF1  + t * AA + k] = a;
            ws[OFS_AF1T + k * 128 + t] = a;
        }
    }
}

// ---- G = Af1 @ Af1^T ----
__global__ __launch_bounds__(256) void k_gram(float* ws) {
    __shared__ float Ai[8 * AA];
    int t = threadIdx.x;
    int i0 = blockIdx.x * 8;
    for (int e = t; e < 8 * AA; e += 256) Ai[e] = ws[OFS_AF1 + i0 * AA + e];
    __syncthreads();
    int ti = t >> 5, tj = t & 31;
    float a0 = 0, a1 = 0, a2 = 0, a3 = 0;
    for (int k = 0; k < AA; ++k) {
        float a = Ai[ti * AA + k];
        float4 bv = *(const float4*)&ws[OFS_AF1T + k * 128 + tj * 4];
        a0 = fmaf(a, bv.x, a0); a1 = fmaf(a, bv.y, a1);
        a2 = fmaf(a, bv.z, a2); a3 = fmaf(a, bv.w, a3);
    }
    *(float4*)&ws[OFS_G + (i0 + ti) * 128 + tj * 4] = make_float4(a0, a1, a2, a3);
}

// ---- OUT = (IN/trace_in)^2 ; accumulate trace(OUT). PSD => traces in [1/128,1]. ----
__global__ __launch_bounds__(256) void k_square(const float* IN, float* OUT,
                                                const float* tr_in, float* tr_out) {
    __shared__ float R[256];
    int t = threadIdx.x;
    int r0 = blockIdx.x * 2;
    R[t] = IN[r0 * 128 + t];
    __syncthreads();
    float s = tr_in[0];
    float inv2 = 1.0f / (s * s);
    int r = t >> 7, c = t & 127;
    float acc = 0.f;
    const float* Rr = &R[r * 128];
    for (int k = 0; k < 128; ++k) acc = fmaf(Rr[k], IN[k * 128 + c], acc);
    acc *= inv2;
    OUT[(r0 + r) * 128 + c] = acc;
    if (c == r0 + r) atomicAdd(tr_out, acc);
}

// ---- Rayleigh quotient on P ~ G^256: v = P*ones; lam = v'Gv / v'v ----
__global__ __launch_bounds__(128) void k_rayleigh(const float* P, const float* G,
                                                  const float* mu_p, float* sc) {
    __shared__ float v[128];
    __shared__ float red[256];
    int t = threadIdx.x;
    float s = 0.f;
    for (int k = 0; k < 128; ++k) s += P[t * 128 + k];
    v[t] = s;
    __syncthreads();
    float w = 0.f;
    for (int k = 0; k < 128; ++k) w = fmaf(G[t * 128 + k], v[k], w);
    red[t] = v[t] * w;
    red[128 + t] = v[t] * v[t];
    __syncthreads();
    for (int off = 64; off > 0; off >>= 1) {
        if (t < off) { red[t] += red[t + off]; red[128 + t] += red[128 + t + off]; }
        __syncthreads();
    }
    if (t == 0) {
        float lam = red[0] / red[128];               // sigma^2 = lammax(G)
        float mu = fmaxf(mu_p[0], 0.0f);
        sc[16] = 1.0f / (lam * mu);                  // X scale: G/(sigma^2*mu)
        sc[17] = 1.0f / (sqrtf(lam) * sqrtf(mu));    // atom scale: 1/(sigma*sqrt(mu))
    }
}

// ---- X = G*scX ; atoms_n = Af1*scA (both layouts) ----
__global__ __launch_bounds__(256) void k_finalize(float* ws) {
    int idx = blockIdx.x * 256 + threadIdx.x;
    float scX = ws[OFS_SC + 16], scA = ws[OFS_SC + 17];
    if (idx < 16384) {
        ws[OFS_X + idx] = ws[OFS_G + idx] * scX;
    } else {
        int e = idx - 16384;
        if (e < 18432) {
            int n = e / AA, k = e - n * AA;
            float a = ws[OFS_AF1 + e] * scA;
            ws[OFS_AN + e] = a;
            ws[OFS_AT + k * 128 + n] = a;
        }
    }
}

// ---- goal init: copy y -> GOAL ----
__global__ __launch_bounds__(256) void k_goalinit(const float* y, float* goal) {
    int idx = blockIdx.x * 256 + threadIdx.x;
    if (idx < 45000) goal[idx] = y[idx];
}

// ---- patch means of y (fixed across unrolls) ----
__global__ __launch_bounds__(256) void k_patchmean(const float* y, float* pm) {
    int p = blockIdx.x * 256 + threadIdx.x;     // 32768
    int b = p >> 12, pi = (p >> 6) & 63, pj = p & 63;
    const float* yb = y + b * 5625;
    float s = 0.f;
    for (int di = 0; di < 12; ++di) {
        const float* row = yb + (pi + di) * 75 + pj;
        for (int dj = 0; dj < 12; ++dj) s += row[dj];
    }
    pm[p] = s * (1.0f / 144.0f);
}

// ---- q[p][n] = valid-corr(goal, atoms_n); block = (pi, b), 64 pj x 128 n ----
__global__ __launch_bounds__(256) void k_q(const float* goal, const float* At, float* q) {
    __shared__ float Ats[AA * 128];
    __shared__ float gls[12 * 76];
    int t = threadIdx.x;
    int pi = blockIdx.x, b = blockIdx.y;
    for (int it = 0; it < 18; ++it)
        ((float4*)Ats)[t + it * 256] = ((const float4*)At)[t + it * 256];
    for (int e = t; e < 912; e += 256) {
        int r = e / 76, cc = e - r * 76;
        float v = 0.f;
        if (cc < 75) v = goal[b * 5625 + (pi + r) * 75 + cc];
        gls[e] = v;
    }
    __syncthreads();
    int tn = t & 31, tp = t >> 5;   // n0 = 4*tn, pj = 8*tp + r
    float acc[8][4] = {};
    for (int di = 0; di < 12; ++di) {
        #pragma unroll
        for (int dj = 0; dj < 12; ++dj) {
            float a[4];
            *(float4*)a = *(const float4*)&Ats[(di * 12 + dj) * 128 + tn * 4];
            const float* g = &gls[di * 76 + tp * 8 + dj];
            #pragma unroll
            for (int r = 0; r < 8; ++r) {
                float gv = g[r];
                acc[r][0] = fmaf(gv, a[0], acc[r][0]);
                acc[r][1] = fmaf(gv, a[1], acc[r][1]);
                acc[r][2] = fmaf(gv, a[2], acc[r][2]);
                acc[r][3] = fmaf(gv, a[3], acc[r][3]);
            }
        }
    }
    int pbase = (b * 64 + pi) * 64 + tp * 8;
    #pragma unroll
    for (int r = 0; r < 8; ++r)
        *(float4*)&q[(pbase + r) * 128 + tn * 4] = *(float4*)acc[r];
}

// ---- fused FISTA (15 iters) + 1 differentiable step — bf16 MFMA version.
//      32 patches/block, 4 waves. Z@X via mfma_f32_16x16x32_bf16:
//      - X (symmetric) held in registers as bf16 B-fragments (8/wave)
//      - Z staged in LDS as bf16, row stride 136 (16B-aligned, uniform bank use)
//      - epilogue (prox/momentum) on f32 register copies (C/D layout)
//      LDS: 8704 B. ----
__global__ __launch_bounds__(256) void k_fista(const float* Xg, const float* qg, float* cfg,
                                               const float* mu_p, int first) {
    __shared__ unsigned short Zs[32 * 136];
    int t = threadIdx.x;
    int lane = t & 63, w = t >> 6;
    int col = lane & 15, quad = lane >> 4;
    int nb = w * 32;                 // this wave's 32-column slice
    int p0 = blockIdx.x * 32;
    float mu = fmaxf(mu_p[0], 0.0f);

    // ---- X B-fragments (one-time): B[k][n] = X[n][k] by symmetry ----
    short8_t xf[2][4];
    #pragma unroll
    for (int nt = 0; nt < 2; ++nt) {
        #pragma unroll
        for (int s = 0; s < 4; ++s) {
            const float* xp = Xg + (nb + nt * 16 + col) * 128 + s * 32 + quad * 8;
            short8_t v;
            #pragma unroll
            for (int j = 0; j < 8; ++j) v[j] = (short)f2bf(xp[j]);
            xf[nt][s] = v;
        }
    }

    // ---- q, c0, z0 in C/D layout; seed Zs ----
    float qv[2][2][4], cv[2][2][4], zo[2][2][4], cfv[2][2][4];
    #pragma unroll
    for (int mt = 0; mt < 2; ++mt)
        #pragma unroll
        for (int nt = 0; nt < 2; ++nt)
            #pragma unroll
            for (int r = 0; r < 4; ++r) {
                int p = p0 + mt * 16 + quad * 4 + r;
                int n = nb + nt * 16 + col;
                qv[mt][nt][r] = qg[p * 128 + n];
                float c0 = first ? 0.f : cfg[p * 128 + n];
                cv[mt][nt][r] = c0;
                zo[mt][nt][r] = c0;
                Zs[(mt * 16 + quad * 4 + r) * 136 + n] = f2bf(c0);
            }
    __syncthreads();

    float tm = 1.0f;
    #pragma unroll 1
    for (int it = 0; it < 16; ++it) {
        // A-fragments: A[m=col][k=quad*8+j] over 2 M-tiles x 4 K-steps
        short8_t af[2][4];
        #pragma unroll
        for (int mt = 0; mt < 2; ++mt)
            #pragma unroll
            for (int s = 0; s < 4; ++s)
                af[mt][s] = *(const short8_t*)&Zs[(mt * 16 + col) * 136 + s * 32 + quad * 8];

        f32x4 acc[2][2];
        #pragma unroll
        for (int mt = 0; mt < 2; ++mt)
            #pragma unroll
            for (int nt = 0; nt < 2; ++nt)
                acc[mt][nt] = (f32x4){0.f, 0.f, 0.f, 0.f};
        #pragma unroll
        for (int s = 0; s < 4; ++s)
            #pragma unroll
            for (int mt = 0; mt < 2; ++mt)
                #pragma unroll
                for (int nt = 0; nt < 2; ++nt)
                    acc[mt][nt] = __builtin_amdgcn_mfma_f32_16x16x32_bf16(
                        af[mt][s], xf[nt][s], acc[mt][nt], 0, 0, 0);

        if (it < 15) {
            float tnn = 0.5f * (1.0f + sqrtf(1.0f + 4.0f * tm * tm));
            float fm = (tm - 1.0f) / tnn;
            tm = tnn;
            #pragma unroll
            for (int mt = 0; mt < 2; ++mt)
                #pragma unroll
                for (int nt = 0; nt < 2; ++nt)
                    #pragma unroll
                    for (int r = 0; r < 4; ++r) {
                        float a = acc[mt][nt][r];
                        float cn = proxf(zo[mt][nt][r] + mu * (qv[mt][nt][r] - a));
                        float zn = cn + fm * (cn - cv[mt][nt][r]);
                        cv[mt][nt][r] = cn;
                        // it==14: z15 never consumed; stage c15 for the final diff step
                        zo[mt][nt][r] = (it == 14) ? cn : zn;
                    }
            __syncthreads();   // all waves done reading Zs this iteration
            #pragma unroll
            for (int mt = 0; mt < 2; ++mt)
                #pragma unroll
                for (int nt = 0; nt < 2; ++nt)
                    #pragma unroll
                    for (int r = 0; r < 4; ++r)
                        Zs[(mt * 16 + quad * 4 + r) * 136 + nb + nt * 16 + col] =
                            f2bf(zo[mt][nt][r]);
            __syncthreads();   // new Z visible
        } else {
            #pragma unroll
            for (int mt = 0; mt < 2; ++mt)
                #pragma unroll
                for (int nt = 0; nt < 2; ++nt)
                    #pragma unroll
                    for (int r = 0; r < 4; ++r)
                        cfv[mt][nt][r] = proxf(cv[mt][nt][r] +
                                               mu * (qv[mt][nt][r] - acc[mt][nt][r]));
        }
    }
    #pragma unroll
    for (int mt = 0; mt < 2; ++mt)
        #pragma unroll
        for (int nt = 0; nt < 2; ++nt)
            #pragma unroll
            for (int r = 0; r < 4; ++r)
                cfg[(p0 + mt * 16 + quad * 4 + r) * 128 + nb + nt * 16 + col] =
                    cfv[mt][nt][r];
}

// ---- pred[p][144] = cf[p,:] @ atoms_n + patch_mean[p]; 64 patches/block ----
__global__ __launch_bounds__(256) void k_pred(const float* AN, const float* cfg,
                                              const float* pm, float* pred) {
    __shared__ float As[128 * AA];
    __shared__ float Cs[64 * 129];
    int t = threadIdx.x;
    int p0 = blockIdx.x * 64;
    for (int it = 0; it < 18; ++it)
        ((float4*)As)[t + it * 256] = ((const float4*)AN)[t + it * 256];
    for (int it = 0; it < 8; ++it) {
        int i4 = t + it * 256;                 // < 2048
        int pr = i4 >> 5, nc = (i4 & 31) * 4;
        float v[4];
        *(float4*)v = *(const float4*)&cfg[(p0 + pr) * 128 + nc];
        float* d = &Cs[pr * 129 + nc];
        d[0] = v[0]; d[1] = v[1]; d[2] = v[2]; d[3] = v[3];
    }
    __syncthreads();
    int tj = t & 15, tp = t >> 4;
    int j0 = tj * 9;
    float acc[4][9] = {};
    for (int n = 0; n < 128; ++n) {
        float cv[4];
        #pragma unroll
        for (int i = 0; i < 4; ++i) cv[i] = Cs[(tp * 4 + i) * 129 + n];
        #pragma unroll
        for (int jj = 0; jj < 9; ++jj) {
            float av = As[n * AA + j0 + jj];
            #pragma unroll
            for (int i = 0; i < 4; ++i) acc[i][jj] = fmaf(cv[i], av, acc[i][jj]);
        }
    }
    #pragma unroll
    for (int i = 0; i < 4; ++i) {
        int p = p0 + tp * 4 + i;
        float pmv = pm[p];
        #pragma unroll
        for (int jj = 0; jj < 9; ++jj) pred[p * AA + j0 + jj] = acc[i][jj] + pmv;
    }
}

// ---- fold (overlap-add gather) + goal update; f32 output on final unroll ----
__global__ __launch_bounds__(256) void k_fold(const float* y, const float* beta_p,
                                              const float* pred, float* goal,
                                              float* out, int write_out) {
    int idx = blockIdx.x * 256 + threadIdx.x;
    if (idx >= 5625) return;
    int b = blockIdx.y;
    int i = idx / 75, j = idx - i * 75;
    float S = 0.f;
    for (int di = 0; di < 12; ++di) {
        int pi = i - di;
        if ((unsigned)pi >= 64u) continue;
        int base = (b << 12) + (pi << 6);
        for (int dj = 0; dj < 12; ++dj) {
            int pj = j - dj;
            if ((unsigned)pj >= 64u) continue;
            S += pred[(base + pj) * AA + di * 12 + dj];
        }
    }
    int ci = min(i, 11) - max(i - 63, 0) + 1;
    int cj = min(j, 11) - max(j - 63, 0) + 1;
    float beta = fmaxf(beta_p[0], 0.0f);
    float yv = y[b * 5625 + idx];
    float g = (yv + beta * S) / (1.0f + beta * (float)(ci * cj));
    goal[b * 5625 + idx] = g;
    if (write_out) out[b * 5625 + idx] = g;     // f32 output (reference output dtype)
}

extern "C" void kernel_launch(void* const* d_in, const int* in_sizes, int n_in,
                              void* d_out, int out_size, void* d_ws, size_t ws_size,
                              hipStream_t stream) {
    const float* y     = (const float*)d_in[0];
    const float* atoms = (const float*)d_in[1];
    const float* beta  = (const float*)d_in[2];
    const float* mu    = (const float*)d_in[3];
    float* out = (float*)d_out;
    float* ws = (float*)d_ws;

    k_norm<<<1, 256, 0, stream>>>(atoms, ws);
    k_gram<<<16, 256, 0, stream>>>(ws);
    for (int j = 0; j < 8; ++j) {           // G^(2^8) via trace-normalized squaring
        const float* IN = ws + (j == 0 ? OFS_G : ((j & 1) ? OFS_S0 : OFS_S1));
        float* OUT = ws + ((j & 1) ? OFS_S1 : OFS_S0);
        k_square<<<64, 256, 0, stream>>>(IN, OUT, ws + OFS_SC + j, ws + OFS_SC + j + 1);
    }
    k_rayleigh<<<1, 128, 0, stream>>>(ws + OFS_S1, ws + OFS_G, mu, ws + OFS_SC);
    k_finalize<<<136, 256, 0, stream>>>(ws);
    k_goalinit<<<176, 256, 0, stream>>>(y, ws + OFS_GOAL);
    k_patchmean<<<128, 256, 0, stream>>>(y, ws + OFS_PM);

    for (int u = 0; u < 2; ++u) {
        k_q<<<dim3(64, 8), 256, 0, stream>>>(ws + OFS_GOAL, ws + OFS_AT, ws + OFS_Q);
        k_fista<<<1024, 256, 0, stream>>>(ws + OFS_X, ws + OFS_Q, ws + OFS_CF,
                                          mu, u == 0 ? 1 : 0);
        k_pred<<<512, 256, 0, stream>>>(ws + OFS_AN, ws + OFS_CF, ws + OFS_PM, ws + OFS_PRED);
        k_fold<<<dim3(22, 8), 256, 0, stream>>>(y, beta, ws + OFS_PRED,
                                                ws + OFS_GOAL, out, u == 1 ? 1 : 0);
    }
}

// Round 6
// 364.112 us; speedup vs baseline: 2.2343x; 1.2223x over previous
//
#include <hip/hip_runtime.h>
#include <stdint.h>

// Problem constants
#define AA 144          // ATOM*ATOM
#define LAM 0.1f

// ---- workspace layout (float offsets) ----
#define OFS_SC    0            // 64 scalars: [0..15]=traces, [16]=scX, [17]=scA
#define OFS_AF1   64           // 128*144 row-normalized zero-mean atoms
#define OFS_AF1T  18496        // 144*128 transposed
#define OFS_G     36928        // 128*128 gram
#define OFS_S0    53312        // squaring ping
#define OFS_S1    69696        // squaring pong
#define OFS_X     86080        // final FISTA gram
#define OFS_AN    102464       // atoms_n (n-major)
#define OFS_AT    120896       // atoms_n (k-major)
#define OFS_PM    139328       // 32768 patch means
#define OFS_GOAL  172096       // 45056 goal (f32)
#define OFS_Q     217152       // 32768*128
#define OFS_CF    4411456      // 32768*128
#define OFS_PRED  8605760      // 32768*144
// total = 13,324,352 floats = ~50.9 MB

typedef __attribute__((ext_vector_type(8))) short short8_t;
typedef __attribute__((ext_vector_type(4))) float f32x4;

__device__ __forceinline__ unsigned short f2bf(float f) {
    union { float f; uint32_t u; } x; x.f = f;
    uint32_t u = x.u;
    return (unsigned short)((u + 0x7FFFu + ((u >> 16) & 1u)) >> 16);
}

// ---- setup: per-atom zero-mean unit-norm rows -> Af1, Af1T; init trace slots ----
__global__ __launch_bounds__(256) void k_norm(const float* atoms, float* ws) {
    int t = threadIdx.x;
    if (t >= 128 && t < 144) ws[OFS_SC + (t - 128)] = (t == 128) ? 128.0f : 0.0f;
    if (t < 128) {
        const float* ap = atoms + t * AA;
        float s = 0.f;
        for (int k = 0; k < AA; ++k) s += ap[k];
        float mean = s * (1.0f / 144.0f);
        float ss = 0.f;
        for (int k = 0; k < AA; ++k) { float a = ap[k] - mean; ss = fmaf(a, a, ss); }
        float rn = 1.0f / sqrtf(ss);
        for (int k = 0; k < AA; ++k) {
            float a = (ap[k] - mean) * rn;
            ws[OFS_AF1  + t * AA + k] = a;
            ws[OFS_AF1T + k * 128 + t] = a;
        }
    }
}

// ---- G = Af1 @ Af1^T ----
__global__ __launch_bounds__(256) void k_gram(float* ws) {
    __shared__ float Ai[8 * AA];
    int t = threadIdx.x;
    int i0 = blockIdx.x * 8;
    for (int e = t; e < 8 * AA; e += 256) Ai[e] = ws[OFS_AF1 + i0 * AA + e];
    __syncthreads();
    int ti = t >> 5, tj = t & 31;
    float a0 = 0, a1 = 0, a2 = 0, a3 = 0;
    for (int k = 0; k < AA; ++k) {
        float a = Ai[ti * AA + k];
        float4 bv = *(const float4*)&ws[OFS_AF1T + k * 128 + tj * 4];
        a0 = fmaf(a, bv.x, a0); a1 = fmaf(a, bv.y, a1);
        a2 = fmaf(a, bv.z, a2); a3 = fmaf(a, bv.w, a3);
    }
    *(float4*)&ws[OFS_G + (i0 + ti) * 128 + tj * 4] = make_float4(a0, a1, a2, a3);
}

// ---- OUT = (IN/trace_in)^2 ; accumulate trace(OUT). PSD => traces in [1/128,1]. ----
__global__ __launch_bounds__(256) void k_square(const float* IN, float* OUT,
                                                const float* tr_in, float* tr_out) {
    __shared__ float R[256];
    int t = threadIdx.x;
    int r0 = blockIdx.x * 2;
    R[t] = IN[r0 * 128 + t];
    __syncthreads();
    float s = tr_in[0];
    float inv2 = 1.0f / (s * s);
    int r = t >> 7, c = t & 127;
    float acc = 0.f;
    const float* Rr = &R[r * 128];
    for (int k = 0; k < 128; ++k) acc = fmaf(Rr[k], IN[k * 128 + c], acc);
    acc *= inv2;
    OUT[(r0 + r) * 128 + c] = acc;
    if (c == r0 + r) atomicAdd(tr_out, acc);
}

// ---- Rayleigh quotient on P ~ G^256: v = P*ones; lam = v'Gv / v'v ----
__global__ __launch_bounds__(128) void k_rayleigh(const float* P, const float* G,
                                                  const float* mu_p, float* sc) {
    __shared__ float v[128];
    __shared__ float red[256];
    int t = threadIdx.x;
    float s = 0.f;
    for (int k = 0; k < 128; ++k) s += P[t * 128 + k];
    v[t] = s;
    __syncthreads();
    float w = 0.f;
    for (int k = 0; k < 128; ++k) w = fmaf(G[t * 128 + k], v[k], w);
    red[t] = v[t] * w;
    red[128 + t] = v[t] * v[t];
    __syncthreads();
    for (int off = 64; off > 0; off >>= 1) {
        if (t < off) { red[t] += red[t + off]; red[128 + t] += red[128 + t + off]; }
        __syncthreads();
    }
    if (t == 0) {
        float lam = red[0] / red[128];               // sigma^2 = lammax(G)
        float mu = fmaxf(mu_p[0], 0.0f);
        sc[16] = 1.0f / (lam * mu);                  // X scale: G/(sigma^2*mu)
        sc[17] = 1.0f / (sqrtf(lam) * sqrtf(mu));    // atom scale: 1/(sigma*sqrt(mu))
    }
}

// ---- X = G*scX ; atoms_n = Af1*scA (both layouts) ----
__global__ __launch_bounds__(256) void k_finalize(float* ws) {
    int idx = blockIdx.x * 256 + threadIdx.x;
    float scX = ws[OFS_SC + 16], scA = ws[OFS_SC + 17];
    if (idx < 16384) {
        ws[OFS_X + idx] = ws[OFS_G + idx] * scX;
    } else {
        int e = idx - 16384;
        if (e < 18432) {
            int n = e / AA, k = e - n * AA;
            float a = ws[OFS_AF1 + e] * scA;
            ws[OFS_AN + e] = a;
            ws[OFS_AT + k * 128 + n] = a;
        }
    }
}

// ---- fused: goal init (copy y) + patch means ----
__global__ __launch_bounds__(256) void k_prep(const float* y, float* goal, float* pm) {
    int idx = blockIdx.x * 256 + threadIdx.x;
    if (idx < 45000) goal[idx] = y[idx];
    if (idx < 32768) {
        int b = idx >> 12, pi = (idx >> 6) & 63, pj = idx & 63;
        const float* yb = y + b * 5625;
        float s = 0.f;
        for (int di = 0; di < 12; ++di) {
            const float* row = yb + (pi + di) * 75 + pj;
            #pragma unroll
            for (int dj = 0; dj < 12; ++dj) s += row[dj];
        }
        pm[idx] = s * (1.0f / 144.0f);
    }
}

// ---- q[p][n] = valid-corr(goal, atoms_n); block = (pi, b), 64 pj x 128 n ----
__global__ __launch_bounds__(256) void k_q(const float* goal, const float* At, float* q) {
    __shared__ float Ats[AA * 128];
    __shared__ float gls[12 * 76];
    int t = threadIdx.x;
    int pi = blockIdx.x, b = blockIdx.y;
    for (int it = 0; it < 18; ++it)
        ((float4*)Ats)[t + it * 256] = ((const float4*)At)[t + it * 256];
    for (int e = t; e < 912; e += 256) {
        int r = e / 76, cc = e - r * 76;
        float v = 0.f;
        if (cc < 75) v = goal[b * 5625 + (pi + r) * 75 + cc];
        gls[e] = v;
    }
    __syncthreads();
    int tn = t & 31, tp = t >> 5;   // n0 = 4*tn, pj = 8*tp + r
    float acc[8][4] = {};
    for (int di = 0; di < 12; ++di) {
        #pragma unroll
        for (int dj = 0; dj < 12; ++dj) {
            float a[4];
            *(float4*)a = *(const float4*)&Ats[(di * 12 + dj) * 128 + tn * 4];
            const float* g = &gls[di * 76 + tp * 8 + dj];
            #pragma unroll
            for (int r = 0; r < 8; ++r) {
                float gv = g[r];
                acc[r][0] = fmaf(gv, a[0], acc[r][0]);
                acc[r][1] = fmaf(gv, a[1], acc[r][1]);
                acc[r][2] = fmaf(gv, a[2], acc[r][2]);
                acc[r][3] = fmaf(gv, a[3], acc[r][3]);
            }
        }
    }
    int pbase = (b * 64 + pi) * 64 + tp * 8;
    #pragma unroll
    for (int r = 0; r < 8; ++r)
        *(float4*)&q[(pbase + r) * 128 + tn * 4] = *(float4*)acc[r];
}

// ---- fused FISTA (15 iters) + 1 differentiable step — bf16 MFMA, dbuf Z,
//      dieted epilogue (med3-prox, round-half-up bf16 cvt, 1 sync/iter). ----
__global__ __launch_bounds__(256) void k_fista(const float* Xg, const float* qg, float* cfg,
                                               const float* mu_p, int first) {
    __shared__ unsigned short Zbuf[2][32 * 136];
    int t = threadIdx.x;
    int lane = t & 63, w = t >> 6;
    int col = lane & 15, quad = lane >> 4;
    int nb = w * 32;                 // this wave's 32-column slice
    int p0 = blockIdx.x * 32;
    float mu = fmaxf(mu_p[0], 0.0f);

    // X B-fragments (one-time): B[k][n] = X[n][k] by symmetry
    short8_t xf[2][4];
    #pragma unroll
    for (int nt = 0; nt < 2; ++nt)
        #pragma unroll
        for (int s = 0; s < 4; ++s) {
            const float* xp = Xg + (nb + nt * 16 + col) * 128 + s * 32 + quad * 8;
            short8_t v;
            #pragma unroll
            for (int j = 0; j < 8; ++j) v[j] = (short)f2bf(xp[j]);
            xf[nt][s] = v;
        }

    float qv[2][2][4], cv[2][2][4], zo[2][2][4];
    #pragma unroll
    for (int mt = 0; mt < 2; ++mt)
        #pragma unroll
        for (int nt = 0; nt < 2; ++nt)
            #pragma unroll
            for (int r = 0; r < 4; ++r) {
                int p = p0 + mt * 16 + quad * 4 + r;
                int n = nb + nt * 16 + col;
                qv[mt][nt][r] = qg[p * 128 + n];
                float c0 = first ? 0.f : cfg[p * 128 + n];
                cv[mt][nt][r] = c0;
                zo[mt][nt][r] = c0;
                Zbuf[0][(mt * 16 + quad * 4 + r) * 136 + n] = f2bf(c0);
            }
    __syncthreads();

    f32x4 acc[2][2];
    auto matmul = [&](const unsigned short* Zr) {
        short8_t af[2][4];
        #pragma unroll
        for (int mt = 0; mt < 2; ++mt)
            #pragma unroll
            for (int s = 0; s < 4; ++s)
                af[mt][s] = *(const short8_t*)&Zr[(mt * 16 + col) * 136 + s * 32 + quad * 8];
        #pragma unroll
        for (int mt = 0; mt < 2; ++mt)
            #pragma unroll
            for (int nt = 0; nt < 2; ++nt)
                acc[mt][nt] = (f32x4){0.f, 0.f, 0.f, 0.f};
        #pragma unroll
        for (int s = 0; s < 4; ++s)
            #pragma unroll
            for (int mt = 0; mt < 2; ++mt)
                #pragma unroll
                for (int nt = 0; nt < 2; ++nt)
                    acc[mt][nt] = __builtin_amdgcn_mfma_f32_16x16x32_bf16(
                        af[mt][s], xf[nt][s], acc[mt][nt], 0, 0, 0);
    };

    float tm = 1.0f;
    int cur = 0;
    #pragma unroll 1
    for (int it = 0; it < 14; ++it) {          // FISTA iters 1..14 (write z)
        matmul(Zbuf[cur]);
        float tnn = 0.5f * (1.0f + sqrtf(1.0f + 4.0f * tm * tm));
        float fm = (tm - 1.0f) / tnn;
        tm = tnn;
        unsigned short* Zw = Zbuf[cur ^ 1];
        #pragma unroll
        for (int mt = 0; mt < 2; ++mt)
            #pragma unroll
            for (int nt = 0; nt < 2; ++nt)
                #pragma unroll
                for (int r = 0; r < 4; ++r) {
                    float df = qv[mt][nt][r] - acc[mt][nt][r];
                    float u = fmaf(mu, df, zo[mt][nt][r]);
                    float cl = fminf(fmaxf(u, -LAM), LAM);     // v_med3
                    float cn = u - cl;                         // prox
                    float d = cn - cv[mt][nt][r];
                    float zn = fmaf(fm, d, cn);
                    cv[mt][nt][r] = cn;
                    zo[mt][nt][r] = zn;
                    union { float f; uint32_t u32; } x; x.f = zn;
                    Zw[(mt * 16 + quad * 4 + r) * 136 + nb + nt * 16 + col] =
                        (unsigned short)((x.u32 + 0x8000u) >> 16);
                }
        __syncthreads();
        cur ^= 1;
    }
    {   // FISTA iter 15: compute c15; stage c15 (z15 never consumed)
        matmul(Zbuf[cur]);
        unsigned short* Zw = Zbuf[cur ^ 1];
        #pragma unroll
        for (int mt = 0; mt < 2; ++mt)
            #pragma unroll
            for (int nt = 0; nt < 2; ++nt)
                #pragma unroll
                for (int r = 0; r < 4; ++r) {
                    float df = qv[mt][nt][r] - acc[mt][nt][r];
                    float u = fmaf(mu, df, zo[mt][nt][r]);
                    float cl = fminf(fmaxf(u, -LAM), LAM);
                    float cn = u - cl;
                    cv[mt][nt][r] = cn;
                    union { float f; uint32_t u32; } x; x.f = cn;
                    Zw[(mt * 16 + quad * 4 + r) * 136 + nb + nt * 16 + col] =
                        (unsigned short)((x.u32 + 0x8000u) >> 16);
                }
        __syncthreads();
        cur ^= 1;
    }
    {   // final differentiable step: cf = prox(c15 + mu*(q - X@c15))
        matmul(Zbuf[cur]);
        #pragma unroll
        for (int mt = 0; mt < 2; ++mt)
            #pragma unroll
            for (int nt = 0; nt < 2; ++nt)
                #pragma unroll
                for (int r = 0; r < 4; ++r) {
                    float df = qv[mt][nt][r] - acc[mt][nt][r];
                    float u = fmaf(mu, df, cv[mt][nt][r]);
                    float cl = fminf(fmaxf(u, -LAM), LAM);
                    cfg[(p0 + mt * 16 + quad * 4 + r) * 128 + nb + nt * 16 + col] = u - cl;
                }
    }
}

// ---- pred[p][144] = cf[p,:] @ atoms_n + patch_mean[p]; 64 patches/block ----
__global__ __launch_bounds__(256) void k_pred(const float* AN, const float* cfg,
                                              const float* pm, float* pred) {
    __shared__ float As[128 * AA];
    __shared__ float Cs[64 * 129];
    int t = threadIdx.x;
    int p0 = blockIdx.x * 64;
    for (int it = 0; it < 18; ++it)
        ((float4*)As)[t + it * 256] = ((const float4*)AN)[t + it * 256];
    for (int it = 0; it < 8; ++it) {
        int i4 = t + it * 256;                 // < 2048
        int pr = i4 >> 5, nc = (i4 & 31) * 4;
        float v[4];
        *(float4*)v = *(const float4*)&cfg[(p0 + pr) * 128 + nc];
        float* d = &Cs[pr * 129 + nc];
        d[0] = v[0]; d[1] = v[1]; d[2] = v[2]; d[3] = v[3];
    }
    __syncthreads();
    int tj = t & 15, tp = t >> 4;
    int j0 = tj * 9;
    float acc[4][9] = {};
    for (int n = 0; n < 128; ++n) {
        float cv[4];
        #pragma unroll
        for (int i = 0; i < 4; ++i) cv[i] = Cs[(tp * 4 + i) * 129 + n];
        #pragma unroll
        for (int jj = 0; jj < 9; ++jj) {
            float av = As[n * AA + j0 + jj];
            #pragma unroll
            for (int i = 0; i < 4; ++i) acc[i][jj] = fmaf(cv[i], av, acc[i][jj]);
        }
    }
    #pragma unroll
    for (int i = 0; i < 4; ++i) {
        int p = p0 + tp * 4 + i;
        float pmv = pm[p];
        #pragma unroll
        for (int jj = 0; jj < 9; ++jj) pred[p * AA + j0 + jj] = acc[i][jj] + pmv;
    }
}

// ---- fold via LDS staging: block = (output row i, batch b); coalesced pred reads.
//      LDS P[di][pj*13+dj] (stride-13 pad: 13 coprime 32 -> conflict-light). ----
__global__ __launch_bounds__(256) void k_fold(const float* y, const float* beta_p,
                                              const float* pred, float* goal,
                                              float* out, int write_out) {
    __shared__ float P[12 * 832];              // 39,936 B
    int i = blockIdx.x, b = blockIdx.y;
    int t = threadIdx.x;
    for (int di = 0; di < 12; ++di) {
        int pi = i - di;
        if ((unsigned)pi >= 64u) continue;     // uniform per block
        int base = (b << 12) + (pi << 6);
        #pragma unroll
        for (int it = 0; it < 3; ++it) {
            int e = t + it * 256;              // < 768 = 64 pj * 12 dj
            int pj = e / 12, dj = e - pj * 12;
            P[di * 832 + pj * 13 + dj] = pred[(base + pj) * AA + di * 12 + dj];
        }
    }
    __syncthreads();
    if (t >= 75) return;
    int j = t;
    float S = 0.f;
    for (int di = 0; di < 12; ++di) {
        if ((unsigned)(i - di) >= 64u) continue;
        const float* Pd = &P[di * 832];
        #pragma unroll
        for (int dj = 0; dj < 12; ++dj) {
            int pj = j - dj;
            if ((unsigned)pj >= 64u) continue;
            S += Pd[pj * 13 + dj];
        }
    }
    int ci = min(i, 11) - max(i - 63, 0) + 1;
    int cj = min(j, 11) - max(j - 63, 0) + 1;
    float beta = fmaxf(beta_p[0], 0.0f);
    int idx = i * 75 + j;
    float yv = y[b * 5625 + idx];
    float g = (yv + beta * S) / (1.0f + beta * (float)(ci * cj));
    goal[b * 5625 + idx] = g;
    if (write_out) out[b * 5625 + idx] = g;
}

extern "C" void kernel_launch(void* const* d_in, const int* in_sizes, int n_in,
                              void* d_out, int out_size, void* d_ws, size_t ws_size,
                              hipStream_t stream) {
    const float* y     = (const float*)d_in[0];
    const float* atoms = (const float*)d_in[1];
    const float* beta  = (const float*)d_in[2];
    const float* mu    = (const float*)d_in[3];
    float* out = (float*)d_out;
    float* ws = (float*)d_ws;

    k_norm<<<1, 256, 0, stream>>>(atoms, ws);
    k_gram<<<16, 256, 0, stream>>>(ws);
    for (int j = 0; j < 8; ++j) {           // G^(2^8) via trace-normalized squaring
        const float* IN = ws + (j == 0 ? OFS_G : ((j & 1) ? OFS_S0 : OFS_S1));
        float* OUT = ws + ((j & 1) ? OFS_S1 : OFS_S0);
        k_square<<<64, 256, 0, stream>>>(IN, OUT, ws + OFS_SC + j, ws + OFS_SC + j + 1);
    }
    k_rayleigh<<<1, 128, 0, stream>>>(ws + OFS_S1, ws + OFS_G, mu, ws + OFS_SC);
    k_finalize<<<136, 256, 0, stream>>>(ws);
    k_prep<<<176, 256, 0, stream>>>(y, ws + OFS_GOAL, ws + OFS_PM);

    for (int u = 0; u < 2; ++u) {
        k_q<<<dim3(64, 8), 256, 0, stream>>>(ws + OFS_GOAL, ws + OFS_AT, ws + OFS_Q);
        k_fista<<<1024, 256, 0, stream>>>(ws + OFS_X, ws + OFS_Q, ws + OFS_CF,
                                          mu, u == 0 ? 1 : 0);
        k_pred<<<512, 256, 0, stream>>>(ws + OFS_AN, ws + OFS_CF, ws + OFS_PM, ws + OFS_PRED);
        k_fold<<<dim3(75, 8), 256, 0, stream>>>(y, beta, ws + OFS_PRED,
                                                ws + OFS_GOAL, out, u == 1 ? 1 : 0);
    }
}

// Round 7
// 318.034 us; speedup vs baseline: 2.5580x; 1.1449x over previous
//
#include <hip/hip_runtime.h>
#include <stdint.h>

// Problem constants
#define AA 144          // ATOM*ATOM
#define LAM 0.1f

// ---- workspace layout (float offsets) ----
#define OFS_SC    0            // 64 scalars: [0..15]=traces, [16]=scX, [17]=scA
#define OFS_AF1   64           // 128*144 row-normalized zero-mean atoms
#define OFS_AF1T  18496        // 144*128 transposed
#define OFS_G     36928        // 128*128 gram
#define OFS_S0    53312        // squaring ping; later reused as ATB (bf16 atoms, [128][160] u16)
#define OFS_S1    69696        // squaring pong; later reused as ANTB (bf16 atomsT, [144][128] u16)
#define OFS_X     86080        // final FISTA gram
#define OFS_PM    139328       // 32768 patch means
#define OFS_GOAL  172096       // 45056 goal (f32)
#define OFS_Q     217152       // 32768*128
#define OFS_CF    4411456      // 32768*128
#define OFS_PRED  8605760      // 32768*144
#define OFS_ATB   OFS_S0
#define OFS_ANTB  OFS_S1

typedef __attribute__((ext_vector_type(8))) short short8_t;
typedef __attribute__((ext_vector_type(4))) float f32x4;

__device__ __forceinline__ unsigned short f2bf(float f) {      // RNE
    union { float f; uint32_t u; } x; x.f = f;
    uint32_t u = x.u;
    return (unsigned short)((u + 0x7FFFu + ((u >> 16) & 1u)) >> 16);
}
__device__ __forceinline__ unsigned short f2bh(float f) {      // round-half-up (cheap)
    union { float f; uint32_t u; } x; x.f = f;
    return (unsigned short)((x.u + 0x8000u) >> 16);
}

// ---- setup: per-atom zero-mean unit-norm rows -> Af1, Af1T; init trace slots ----
__global__ __launch_bounds__(256) void k_norm(const float* atoms, float* ws) {
    int t = threadIdx.x;
    if (t >= 128 && t < 144) ws[OFS_SC + (t - 128)] = (t == 128) ? 128.0f : 0.0f;
    if (t < 128) {
        const float* ap = atoms + t * AA;
        float s = 0.f;
        for (int k = 0; k < AA; ++k) s += ap[k];
        float mean = s * (1.0f / 144.0f);
        float ss = 0.f;
        for (int k = 0; k < AA; ++k) { float a = ap[k] - mean; ss = fmaf(a, a, ss); }
        float rn = 1.0f / sqrtf(ss);
        for (int k = 0; k < AA; ++k) {
            float a = (ap[k] - mean) * rn;
            ws[OFS_AF1  + t * AA + k] = a;
            ws[OFS_AF1T + k * 128 + t] = a;
        }
    }
}

// ---- G = Af1 @ Af1^T ----
__global__ __launch_bounds__(256) void k_gram(float* ws) {
    __shared__ float Ai[8 * AA];
    int t = threadIdx.x;
    int i0 = blockIdx.x * 8;
    for (int e = t; e < 8 * AA; e += 256) Ai[e] = ws[OFS_AF1 + i0 * AA + e];
    __syncthreads();
    int ti = t >> 5, tj = t & 31;
    float a0 = 0, a1 = 0, a2 = 0, a3 = 0;
    for (int k = 0; k < AA; ++k) {
        float a = Ai[ti * AA + k];
        float4 bv = *(const float4*)&ws[OFS_AF1T + k * 128 + tj * 4];
        a0 = fmaf(a, bv.x, a0); a1 = fmaf(a, bv.y, a1);
        a2 = fmaf(a, bv.z, a2); a3 = fmaf(a, bv.w, a3);
    }
    *(float4*)&ws[OFS_G + (i0 + ti) * 128 + tj * 4] = make_float4(a0, a1, a2, a3);
}

// ---- OUT = (IN/trace_in)^2 via LDS-staged IN (coalesced); trace accumulated. ----
__global__ __launch_bounds__(256) void k_square(const float* IN, float* OUT,
                                                const float* tr_in, float* tr_out) {
    __shared__ float M[16384];
    int t = threadIdx.x;
    #pragma unroll
    for (int it = 0; it < 16; ++it)
        ((float4*)M)[t + it * 256] = ((const float4*)IN)[t + it * 256];
    __syncthreads();
    int r0 = blockIdx.x * 2;
    float s = tr_in[0];
    float inv2 = 1.0f / (s * s);
    int r = t >> 7, c = t & 127;
    const float* Rr = &M[(r0 + r) * 128];          // broadcast row
    float acc = 0.f;
    for (int k = 0; k < 128; ++k) acc = fmaf(Rr[k], M[k * 128 + c], acc);  // col: 2-way free
    acc *= inv2;
    OUT[(r0 + r) * 128 + c] = acc;
    if (c == r0 + r) atomicAdd(tr_out, acc);
}

// ---- Rayleigh quotient on P ~ G^256: v = P*ones; lam = v'Gv / v'v ----
__global__ __launch_bounds__(128) void k_rayleigh(const float* P, const float* G,
                                                  const float* mu_p, float* sc) {
    __shared__ float v[128];
    __shared__ float red[256];
    int t = threadIdx.x;
    float s = 0.f;
    for (int k = 0; k < 128; ++k) s += P[t * 128 + k];
    v[t] = s;
    __syncthreads();
    float w = 0.f;
    for (int k = 0; k < 128; ++k) w = fmaf(G[t * 128 + k], v[k], w);
    red[t] = v[t] * w;
    red[128 + t] = v[t] * v[t];
    __syncthreads();
    for (int off = 64; off > 0; off >>= 1) {
        if (t < off) { red[t] += red[t + off]; red[128 + t] += red[128 + t + off]; }
        __syncthreads();
    }
    if (t == 0) {
        float lam = red[0] / red[128];               // sigma^2 = lammax(G)
        float mu = fmaxf(mu_p[0], 0.0f);
        sc[16] = 1.0f / (lam * mu);                  // X scale: G/(sigma^2*mu)
        sc[17] = 1.0f / (sqrtf(lam) * sqrtf(mu));    // atom scale: 1/(sigma*sqrt(mu))
    }
}

// ---- finalize (fused): X = G*scX ; ATB/ANTB bf16 weights ; goal=y ; patch means ----
__global__ __launch_bounds__(256) void k_finalize(float* ws, const float* y) {
    int idx = blockIdx.x * 256 + threadIdx.x;       // grid 392 -> 100352
    float scX = ws[OFS_SC + 16], scA = ws[OFS_SC + 17];
    if (idx < 16384) {
        ws[OFS_X + idx] = ws[OFS_G + idx] * scX;
    } else if (idx < 36864) {
        int e = idx - 16384;                        // ATB [n=128][k=160] (zero-pad k>=144)
        int n = e / 160, k = e - n * 160;
        float v = (k < 144) ? ws[OFS_AF1 + n * 144 + k] * scA : 0.f;
        ((unsigned short*)(ws + OFS_ATB))[e] = f2bf(v);
    } else if (idx < 55296) {
        int e = idx - 36864;                        // ANTB [j=144][n=128]
        int j = e / 128, n = e - j * 128;
        ((unsigned short*)(ws + OFS_ANTB))[e] = f2bf(ws[OFS_AF1 + n * 144 + j] * scA);
    } else {
        int e = idx - 55296;                        // < 45056
        if (e < 45000) ws[OFS_GOAL + e] = y[e];
        if (e < 32768) {
            int b = e >> 12, pi = (e >> 6) & 63, pj = e & 63;
            const float* yb = y + b * 5625;
            float s = 0.f;
            for (int di = 0; di < 12; ++di) {
                const float* row = yb + (pi + di) * 75 + pj;
                #pragma unroll
                for (int dj = 0; dj < 12; ++dj) s += row[dj];
            }
            ws[OFS_PM + e] = s * (1.0f / 144.0f);
        }
    }
}

// ---- q = im2col(goal) @ atoms^T via bf16 MFMA. Block=(pi,b): 64 pj x 128 n, K=144->160.
//      A-tile LDS stride 168 u16: 84m mod 32 covers all bank-quads -> 2-way (free). ----
__global__ __launch_bounds__(256) void k_q(const float* goal, const unsigned short* ATB,
                                           float* q) {
    __shared__ float gls[12 * 76];
    __shared__ unsigned short Atile[64 * 168];
    int t = threadIdx.x;
    int pi = blockIdx.x, b = blockIdx.y;
    for (int e = t; e < 912; e += 256) {
        int r = e / 76, cc = e - r * 76;
        float v = 0.f;
        if (cc < 75) v = goal[b * 5625 + (pi + r) * 75 + cc];
        gls[e] = v;
    }
    __syncthreads();
    #pragma unroll
    for (int i = 0; i < 40; ++i) {
        int e = t + i * 256;                       // < 10240 = 64m * 160k
        int m = e / 160, k = e - m * 160;
        float v = 0.f;
        if (k < 144) {
            int di = k / 12, dj = k - di * 12;
            v = gls[di * 76 + m + dj];
        }
        Atile[m * 168 + k] = f2bh(v);
    }
    __syncthreads();
    int lane = t & 63, w = t >> 6;
    int col = lane & 15, quad = lane >> 4;
    int wn = w * 32;                               // wave's 32 atoms
    short8_t bf[2][5];
    #pragma unroll
    for (int nt = 0; nt < 2; ++nt)
        #pragma unroll
        for (int s = 0; s < 5; ++s)
            bf[nt][s] = *(const short8_t*)&ATB[(wn + nt * 16 + col) * 160 + s * 32 + quad * 8];
    int pbase = (b * 64 + pi) * 64;
    #pragma unroll
    for (int mt = 0; mt < 4; ++mt) {
        short8_t af[5];
        #pragma unroll
        for (int s = 0; s < 5; ++s)
            af[s] = *(const short8_t*)&Atile[(mt * 16 + col) * 168 + s * 32 + quad * 8];
        f32x4 acc0 = (f32x4){0.f, 0.f, 0.f, 0.f};
        f32x4 acc1 = (f32x4){0.f, 0.f, 0.f, 0.f};
        #pragma unroll
        for (int s = 0; s < 5; ++s) {
            acc0 = __builtin_amdgcn_mfma_f32_16x16x32_bf16(af[s], bf[0][s], acc0, 0, 0, 0);
            acc1 = __builtin_amdgcn_mfma_f32_16x16x32_bf16(af[s], bf[1][s], acc1, 0, 0, 0);
        }
        #pragma unroll
        for (int r = 0; r < 4; ++r) {
            int p = pbase + mt * 16 + quad * 4 + r;
            q[p * 128 + wn + col] = acc0[r];
            q[p * 128 + wn + 16 + col] = acc1[r];
        }
    }
}

// ---- fused FISTA (15 iters) + 1 differentiable step — bf16 MFMA, dbuf Z. ----
__global__ __launch_bounds__(256) void k_fista(const float* Xg, const float* qg, float* cfg,
                                               const float* mu_p, int first) {
    __shared__ unsigned short Zbuf[2][32 * 136];
    int t = threadIdx.x;
    int lane = t & 63, w = t >> 6;
    int col = lane & 15, quad = lane >> 4;
    int nb = w * 32;                 // this wave's 32-column slice
    int p0 = blockIdx.x * 32;
    float mu = fmaxf(mu_p[0], 0.0f);

    short8_t xf[2][4];
    #pragma unroll
    for (int nt = 0; nt < 2; ++nt)
        #pragma unroll
        for (int s = 0; s < 4; ++s) {
            const float* xp = Xg + (nb + nt * 16 + col) * 128 + s * 32 + quad * 8;
            short8_t v;
            #pragma unroll
            for (int j = 0; j < 8; ++j) v[j] = (short)f2bf(xp[j]);
            xf[nt][s] = v;
        }

    float qv[2][2][4], cv[2][2][4], zo[2][2][4];
    #pragma unroll
    for (int mt = 0; mt < 2; ++mt)
        #pragma unroll
        for (int nt = 0; nt < 2; ++nt)
            #pragma unroll
            for (int r = 0; r < 4; ++r) {
                int p = p0 + mt * 16 + quad * 4 + r;
                int n = nb + nt * 16 + col;
                qv[mt][nt][r] = qg[p * 128 + n];
                float c0 = first ? 0.f : cfg[p * 128 + n];
                cv[mt][nt][r] = c0;
                zo[mt][nt][r] = c0;
                Zbuf[0][(mt * 16 + quad * 4 + r) * 136 + n] = f2bf(c0);
            }
    __syncthreads();

    f32x4 acc[2][2];
    auto matmul = [&](const unsigned short* Zr) {
        short8_t af[2][4];
        #pragma unroll
        for (int mt = 0; mt < 2; ++mt)
            #pragma unroll
            for (int s = 0; s < 4; ++s)
                af[mt][s] = *(const short8_t*)&Zr[(mt * 16 + col) * 136 + s * 32 + quad * 8];
        #pragma unroll
        for (int mt = 0; mt < 2; ++mt)
            #pragma unroll
            for (int nt = 0; nt < 2; ++nt)
                acc[mt][nt] = (f32x4){0.f, 0.f, 0.f, 0.f};
        #pragma unroll
        for (int s = 0; s < 4; ++s)
            #pragma unroll
            for (int mt = 0; mt < 2; ++mt)
                #pragma unroll
                for (int nt = 0; nt < 2; ++nt)
                    acc[mt][nt] = __builtin_amdgcn_mfma_f32_16x16x32_bf16(
                        af[mt][s], xf[nt][s], acc[mt][nt], 0, 0, 0);
    };

    float tm = 1.0f;
    int cur = 0;
    #pragma unroll 1
    for (int it = 0; it < 14; ++it) {          // FISTA iters 1..14 (write z)
        matmul(Zbuf[cur]);
        float tnn = 0.5f * (1.0f + sqrtf(1.0f + 4.0f * tm * tm));
        float fm = (tm - 1.0f) / tnn;
        tm = tnn;
        unsigned short* Zw = Zbuf[cur ^ 1];
        #pragma unroll
        for (int mt = 0; mt < 2; ++mt)
            #pragma unroll
            for (int nt = 0; nt < 2; ++nt)
                #pragma unroll
                for (int r = 0; r < 4; ++r) {
                    float df = qv[mt][nt][r] - acc[mt][nt][r];
                    float u = fmaf(mu, df, zo[mt][nt][r]);
                    float cl = fminf(fmaxf(u, -LAM), LAM);
                    float cn = u - cl;
                    float d = cn - cv[mt][nt][r];
                    float zn = fmaf(fm, d, cn);
                    cv[mt][nt][r] = cn;
                    zo[mt][nt][r] = zn;
                    Zw[(mt * 16 + quad * 4 + r) * 136 + nb + nt * 16 + col] = f2bh(zn);
                }
        __syncthreads();
        cur ^= 1;
    }
    {   // FISTA iter 15: compute c15; stage c15 (z15 never consumed)
        matmul(Zbuf[cur]);
        unsigned short* Zw = Zbuf[cur ^ 1];
        #pragma unroll
        for (int mt = 0; mt < 2; ++mt)
            #pragma unroll
            for (int nt = 0; nt < 2; ++nt)
                #pragma unroll
                for (int r = 0; r < 4; ++r) {
                    float df = qv[mt][nt][r] - acc[mt][nt][r];
                    float u = fmaf(mu, df, zo[mt][nt][r]);
                    float cl = fminf(fmaxf(u, -LAM), LAM);
                    float cn = u - cl;
                    cv[mt][nt][r] = cn;
                    Zw[(mt * 16 + quad * 4 + r) * 136 + nb + nt * 16 + col] = f2bh(cn);
                }
        __syncthreads();
        cur ^= 1;
    }
    {   // final differentiable step: cf = prox(c15 + mu*(q - X@c15))
        matmul(Zbuf[cur]);
        #pragma unroll
        for (int mt = 0; mt < 2; ++mt)
            #pragma unroll
            for (int nt = 0; nt < 2; ++nt)
                #pragma unroll
                for (int r = 0; r < 4; ++r) {
                    float df = qv[mt][nt][r] - acc[mt][nt][r];
                    float u = fmaf(mu, df, cv[mt][nt][r]);
                    float cl = fminf(fmaxf(u, -LAM), LAM);
                    cfg[(p0 + mt * 16 + quad * 4 + r) * 128 + nb + nt * 16 + col] = u - cl;
                }
    }
}

// ---- pred = cf @ atoms_n + pm via bf16 MFMA. Block: 64 patches x 144 j, K=128.
//      9 j-tiles split 3/2/2/2 across waves; A = cf f32 -> bf16 in-reg. ----
__global__ __launch_bounds__(256) void k_pred(const unsigned short* ANTB, const float* cfg,
                                              const float* pm, float* pred) {
    int t = threadIdx.x;
    int lane = t & 63, w = t >> 6;
    int col = lane & 15, quad = lane >> 4;
    int p0 = blockIdx.x * 64;
    int jt0 = (w == 0) ? 0 : (2 * w + 1);
    int jtn = (w == 0) ? 3 : 2;
    short8_t af[4][4];
    #pragma unroll
    for (int mt = 0; mt < 4; ++mt)
        #pragma unroll
        for (int s = 0; s < 4; ++s) {
            const float* cp = &cfg[(p0 + mt * 16 + col) * 128 + s * 32 + quad * 8];
            float4 lo = *(const float4*)cp;
            float4 hi = *(const float4*)(cp + 4);
            short8_t v;
            v[0] = (short)f2bh(lo.x); v[1] = (short)f2bh(lo.y);
            v[2] = (short)f2bh(lo.z); v[3] = (short)f2bh(lo.w);
            v[4] = (short)f2bh(hi.x); v[5] = (short)f2bh(hi.y);
            v[6] = (short)f2bh(hi.z); v[7] = (short)f2bh(hi.w);
            af[mt][s] = v;
        }
    f32x4 acc[4][3];
    #pragma unroll
    for (int mt = 0; mt < 4; ++mt)
        #pragma unroll
        for (int ji = 0; ji < 3; ++ji)
            acc[mt][ji] = (f32x4){0.f, 0.f, 0.f, 0.f};
    #pragma unroll
    for (int ji = 0; ji < 3; ++ji) {
        if (ji < jtn) {
            int jt = jt0 + ji;
            short8_t bf4[4];
            #pragma unroll
            for (int s = 0; s < 4; ++s)
                bf4[s] = *(const short8_t*)&ANTB[(jt * 16 + col) * 128 + s * 32 + quad * 8];
            #pragma unroll
            for (int mt = 0; mt < 4; ++mt)
                #pragma unroll
                for (int s = 0; s < 4; ++s)
                    acc[mt][ji] = __builtin_amdgcn_mfma_f32_16x16x32_bf16(
                        af[mt][s], bf4[s], acc[mt][ji], 0, 0, 0);
        }
    }
    #pragma unroll
    for (int mt = 0; mt < 4; ++mt)
        #pragma unroll
        for (int r = 0; r < 4; ++r) {
            int p = p0 + mt * 16 + quad * 4 + r;
            float pmv = pm[p];
            #pragma unroll
            for (int ji = 0; ji < 3; ++ji)
                if (ji < jtn)
                    pred[p * 144 + (jt0 + ji) * 16 + col] = acc[mt][ji][r] + pmv;
        }
}

// ---- fold via LDS staging: block = (output row i, batch b); coalesced pred reads. ----
__global__ __launch_bounds__(256) void k_fold(const float* y, const float* beta_p,
                                              const float* pred, float* goal,
                                              float* out, int write_out) {
    __shared__ float P[12 * 832];              // 39,936 B
    int i = blockIdx.x, b = blockIdx.y;
    int t = threadIdx.x;
    for (int di = 0; di < 12; ++di) {
        int pi = i - di;
        if ((unsigned)pi >= 64u) continue;     // uniform per block
        int base = (b << 12) + (pi << 6);
        #pragma unroll
        for (int it = 0; it < 3; ++it) {
            int e = t + it * 256;              // < 768 = 64 pj * 12 dj
            int pj = e / 12, dj = e - pj * 12;
            P[di * 832 + pj * 13 + dj] = pred[(base + pj) * AA + di * 12 + dj];
        }
    }
    __syncthreads();
    if (t >= 75) return;
    int j = t;
    float S = 0.f;
    for (int di = 0; di < 12; ++di) {
        if ((unsigned)(i - di) >= 64u) continue;
        const float* Pd = &P[di * 832];
        #pragma unroll
        for (int dj = 0; dj < 12; ++dj) {
            int pj = j - dj;
            if ((unsigned)pj >= 64u) continue;
            S += Pd[pj * 13 + dj];
        }
    }
    int ci = min(i, 11) - max(i - 63, 0) + 1;
    int cj = min(j, 11) - max(j - 63, 0) + 1;
    float beta = fmaxf(beta_p[0], 0.0f);
    int idx = i * 75 + j;
    float yv = y[b * 5625 + idx];
    float g = (yv + beta * S) / (1.0f + beta * (float)(ci * cj));
    goal[b * 5625 + idx] = g;
    if (write_out) out[b * 5625 + idx] = g;
}

extern "C" void kernel_launch(void* const* d_in, const int* in_sizes, int n_in,
                              void* d_out, int out_size, void* d_ws, size_t ws_size,
                              hipStream_t stream) {
    const float* y     = (const float*)d_in[0];
    const float* atoms = (const float*)d_in[1];
    const float* beta  = (const float*)d_in[2];
    const float* mu    = (const float*)d_in[3];
    float* out = (float*)d_out;
    float* ws = (float*)d_ws;

    k_norm<<<1, 256, 0, stream>>>(atoms, ws);
    k_gram<<<16, 256, 0, stream>>>(ws);
    for (int j = 0; j < 8; ++j) {           // G^(2^8) via trace-normalized squaring
        const float* IN = ws + (j == 0 ? OFS_G : ((j & 1) ? OFS_S0 : OFS_S1));
        float* OUT = ws + ((j & 1) ? OFS_S1 : OFS_S0);
        k_square<<<64, 256, 0, stream>>>(IN, OUT, ws + OFS_SC + j, ws + OFS_SC + j + 1);
    }
    k_rayleigh<<<1, 128, 0, stream>>>(ws + OFS_S1, ws + OFS_G, mu, ws + OFS_SC);
    k_finalize<<<392, 256, 0, stream>>>(ws, y);     // X + bf16 weights + goal + patchmean

    for (int u = 0; u < 2; ++u) {
        k_q<<<dim3(64, 8), 256, 0, stream>>>(ws + OFS_GOAL,
                                             (const unsigned short*)(ws + OFS_ATB),
                                             ws + OFS_Q);
        k_fista<<<1024, 256, 0, stream>>>(ws + OFS_X, ws + OFS_Q, ws + OFS_CF,
                                          mu, u == 0 ? 1 : 0);
        k_pred<<<512, 256, 0, stream>>>((const unsigned short*)(ws + OFS_ANTB),
                                        ws + OFS_CF, ws + OFS_PM, ws + OFS_PRED);
        k_fold<<<dim3(75, 8), 256, 0, stream>>>(y, beta, ws + OFS_PRED,
                                                ws + OFS_GOAL, out, u == 1 ? 1 : 0);
    }
}

// Round 8
// 291.789 us; speedup vs baseline: 2.7881x; 1.0899x over previous
//
#include <hip/hip_runtime.h>
#include <stdint.h>

// Problem constants
#define AA 144          // ATOM*ATOM
#define LAM 0.1f

// ---- workspace layout (float offsets) ----
#define OFS_SC    0            // 64 scalars: [0..15]=traces, [16]=scX, [17]=scA
#define OFS_AF1   64           // 128*144 row-normalized zero-mean atoms
#define OFS_AF1T  18496        // 144*128 transposed
#define OFS_G     36928        // 128*128 gram
#define OFS_S0    53312        // squaring ping; later reused as ATB (bf16 atoms, [128][160] u16)
#define OFS_S1    69696        // squaring pong; later reused as ANTB (bf16 atomsT, [144][128] u16)
#define OFS_X     86080        // final FISTA gram
#define OFS_PM    139328       // 32768 patch means
#define OFS_GOAL  172096       // 45056 goal (f32)
#define OFS_CF    4411456      // 32768*128
#define OFS_PRED  8605760      // 32768*144
#define OFS_ATB   OFS_S0
#define OFS_ANTB  OFS_S1

typedef __attribute__((ext_vector_type(8))) short short8_t;
typedef __attribute__((ext_vector_type(4))) float f32x4;

__device__ __forceinline__ unsigned short f2bf(float f) {      // RNE
    union { float f; uint32_t u; } x; x.f = f;
    uint32_t u = x.u;
    return (unsigned short)((u + 0x7FFFu + ((u >> 16) & 1u)) >> 16);
}
__device__ __forceinline__ unsigned short f2bh(float f) {      // round-half-up (cheap)
    union { float f; uint32_t u; } x; x.f = f;
    return (unsigned short)((x.u + 0x8000u) >> 16);
}

// ---- setup: per-atom zero-mean unit-norm rows -> Af1, Af1T; init trace slots ----
__global__ __launch_bounds__(256) void k_norm(const float* atoms, float* ws) {
    int t = threadIdx.x;
    if (t >= 128 && t < 144) ws[OFS_SC + (t - 128)] = (t == 128) ? 128.0f : 0.0f;
    if (t < 128) {
        const float* ap = atoms + t * AA;
        float s = 0.f;
        for (int k = 0; k < AA; ++k) s += ap[k];
        float mean = s * (1.0f / 144.0f);
        float ss = 0.f;
        for (int k = 0; k < AA; ++k) { float a = ap[k] - mean; ss = fmaf(a, a, ss); }
        float rn = 1.0f / sqrtf(ss);
        for (int k = 0; k < AA; ++k) {
            float a = (ap[k] - mean) * rn;
            ws[OFS_AF1  + t * AA + k] = a;
            ws[OFS_AF1T + k * 128 + t] = a;
        }
    }
}

// ---- G = Af1 @ Af1^T ----
__global__ __launch_bounds__(256) void k_gram(float* ws) {
    __shared__ float Ai[8 * AA];
    int t = threadIdx.x;
    int i0 = blockIdx.x * 8;
    for (int e = t; e < 8 * AA; e += 256) Ai[e] = ws[OFS_AF1 + i0 * AA + e];
    __syncthreads();
    int ti = t >> 5, tj = t & 31;
    float a0 = 0, a1 = 0, a2 = 0, a3 = 0;
    for (int k = 0; k < AA; ++k) {
        float a = Ai[ti * AA + k];
        float4 bv = *(const float4*)&ws[OFS_AF1T + k * 128 + tj * 4];
        a0 = fmaf(a, bv.x, a0); a1 = fmaf(a, bv.y, a1);
        a2 = fmaf(a, bv.z, a2); a3 = fmaf(a, bv.w, a3);
    }
    *(float4*)&ws[OFS_G + (i0 + ti) * 128 + tj * 4] = make_float4(a0, a1, a2, a3);
}

// ---- OUT = (IN/trace_in)^2 via LDS-staged IN (coalesced); trace accumulated. ----
__global__ __launch_bounds__(256) void k_square(const float* IN, float* OUT,
                                                const float* tr_in, float* tr_out) {
    __shared__ float M[16384];
    int t = threadIdx.x;
    #pragma unroll
    for (int it = 0; it < 16; ++it)
        ((float4*)M)[t + it * 256] = ((const float4*)IN)[t + it * 256];
    __syncthreads();
    int r0 = blockIdx.x * 2;
    float s = tr_in[0];
    float inv2 = 1.0f / (s * s);
    int r = t >> 7, c = t & 127;
    const float* Rr = &M[(r0 + r) * 128];          // broadcast row
    float acc = 0.f;
    for (int k = 0; k < 128; ++k) acc = fmaf(Rr[k], M[k * 128 + c], acc);  // col: 2-way free
    acc *= inv2;
    OUT[(r0 + r) * 128 + c] = acc;
    if (c == r0 + r) atomicAdd(tr_out, acc);
}

// ---- Rayleigh quotient on P ~ G^256: v = P*ones; lam = v'Gv / v'v ----
__global__ __launch_bounds__(128) void k_rayleigh(const float* P, const float* G,
                                                  const float* mu_p, float* sc) {
    __shared__ float v[128];
    __shared__ float red[256];
    int t = threadIdx.x;
    float s = 0.f;
    for (int k = 0; k < 128; ++k) s += P[t * 128 + k];
    v[t] = s;
    __syncthreads();
    float w = 0.f;
    for (int k = 0; k < 128; ++k) w = fmaf(G[t * 128 + k], v[k], w);
    red[t] = v[t] * w;
    red[128 + t] = v[t] * v[t];
    __syncthreads();
    for (int off = 64; off > 0; off >>= 1) {
        if (t < off) { red[t] += red[t + off]; red[128 + t] += red[128 + t + off]; }
        __syncthreads();
    }
    if (t == 0) {
        float lam = red[0] / red[128];               // sigma^2 = lammax(G)
        float mu = fmaxf(mu_p[0], 0.0f);
        sc[16] = 1.0f / (lam * mu);                  // X scale: G/(sigma^2*mu)
        sc[17] = 1.0f / (sqrtf(lam) * sqrtf(mu));    // atom scale: 1/(sigma*sqrt(mu))
    }
}

// ---- finalize (fused): X = G*scX ; ATB/ANTB bf16 weights ; goal=y ; patch means ----
__global__ __launch_bounds__(256) void k_finalize(float* ws, const float* y) {
    int idx = blockIdx.x * 256 + threadIdx.x;       // grid 392 -> 100352
    float scX = ws[OFS_SC + 16], scA = ws[OFS_SC + 17];
    if (idx < 16384) {
        ws[OFS_X + idx] = ws[OFS_G + idx] * scX;
    } else if (idx < 36864) {
        int e = idx - 16384;                        // ATB [n=128][k=160] (zero-pad k>=144)
        int n = e / 160, k = e - n * 160;
        float v = (k < 144) ? ws[OFS_AF1 + n * 144 + k] * scA : 0.f;
        ((unsigned short*)(ws + OFS_ATB))[e] = f2bf(v);
    } else if (idx < 55296) {
        int e = idx - 36864;                        // ANTB [j=144][n=128]
        int j = e / 128, n = e - j * 128;
        ((unsigned short*)(ws + OFS_ANTB))[e] = f2bf(ws[OFS_AF1 + n * 144 + j] * scA);
    } else {
        int e = idx - 55296;                        // < 45056
        if (e < 45000) ws[OFS_GOAL + e] = y[e];
        if (e < 32768) {
            int b = e >> 12, pi = (e >> 6) & 63, pj = e & 63;
            const float* yb = y + b * 5625;
            float s = 0.f;
            for (int di = 0; di < 12; ++di) {
                const float* row = yb + (pi + di) * 75 + pj;
                #pragma unroll
                for (int dj = 0; dj < 12; ++dj) s += row[dj];
            }
            ws[OFS_PM + e] = s * (1.0f / 144.0f);
        }
    }
}

// ---- fused per-unroll megakernel: q (im2col MFMA) + FISTA(15)+1 + pred.
//      Block = 32 patches (b, pi, half-row h). 4 waves; wave w owns atom cols
//      nb..nb+31. LDS: gls 2112 + Atile 10752 + Z dbuf 17408 = 30272 B. ----
__global__ __launch_bounds__(256) void k_fista(const float* Xg, const float* goal,
                                               const unsigned short* ATB,
                                               const unsigned short* ANTB,
                                               const float* pm, float* cfg, float* pred,
                                               const float* mu_p, int first) {
    __shared__ float gls[12 * 44];
    __shared__ unsigned short Atile[32 * 168];
    __shared__ unsigned short Zbuf[2][32 * 136];
    int t = threadIdx.x;
    int lane = t & 63, w = t >> 6;
    int col = lane & 15, quad = lane >> 4;
    int nb = w * 32;
    int blk = blockIdx.x;
    int b = blk >> 7, pi = (blk >> 1) & 63, h = blk & 1;
    int p0 = blk * 32;
    float mu = fmaxf(mu_p[0], 0.0f);

    // ---- stage goal slice (12 x 44, zero-pad past col 74) ----
    for (int e = t; e < 528; e += 256) {
        int r = e / 44, cc = e - r * 44;
        int gc = h * 32 + cc;
        gls[e] = (gc < 75) ? goal[b * 5625 + (pi + r) * 75 + gc] : 0.f;
    }
    __syncthreads();
    // ---- im2col A-tile 32 x 160 bf16 ----
    #pragma unroll
    for (int i = 0; i < 20; ++i) {
        int e = t + i * 256;                   // < 5120
        int m = e / 160, k = e - m * 160;
        float v = 0.f;
        if (k < 144) {
            int di = k / 12, dj = k - di * 12;
            v = gls[di * 44 + m + dj];
        }
        Atile[m * 168 + k] = f2bh(v);
    }
    __syncthreads();

    // ---- q-matmul: qv = im2col @ atoms^T, directly in C/D layout ----
    float qv[2][2][4];
    {
        short8_t bfq[2][5];
        #pragma unroll
        for (int nt = 0; nt < 2; ++nt)
            #pragma unroll
            for (int s = 0; s < 5; ++s)
                bfq[nt][s] = *(const short8_t*)&ATB[(nb + nt * 16 + col) * 160 + s * 32 + quad * 8];
        #pragma unroll
        for (int mt = 0; mt < 2; ++mt) {
            short8_t af[5];
            #pragma unroll
            for (int s = 0; s < 5; ++s)
                af[s] = *(const short8_t*)&Atile[(mt * 16 + col) * 168 + s * 32 + quad * 8];
            f32x4 acc0 = (f32x4){0.f, 0.f, 0.f, 0.f};
            f32x4 acc1 = (f32x4){0.f, 0.f, 0.f, 0.f};
            #pragma unroll
            for (int s = 0; s < 5; ++s) {
                acc0 = __builtin_amdgcn_mfma_f32_16x16x32_bf16(af[s], bfq[0][s], acc0, 0, 0, 0);
                acc1 = __builtin_amdgcn_mfma_f32_16x16x32_bf16(af[s], bfq[1][s], acc1, 0, 0, 0);
            }
            #pragma unroll
            for (int r = 0; r < 4; ++r) { qv[mt][0][r] = acc0[r]; qv[mt][1][r] = acc1[r]; }
        }
    }

    // ---- X B-fragments (symmetric: B[k][n] = X[n][k]) ----
    short8_t xf[2][4];
    #pragma unroll
    for (int nt = 0; nt < 2; ++nt)
        #pragma unroll
        for (int s = 0; s < 4; ++s) {
            const float* xp = Xg + (nb + nt * 16 + col) * 128 + s * 32 + quad * 8;
            short8_t v;
            #pragma unroll
            for (int j = 0; j < 8; ++j) v[j] = (short)f2bf(xp[j]);
            xf[nt][s] = v;
        }

    // ---- c0 / z0 init, seed Z ----
    float cv[2][2][4], zo[2][2][4];
    #pragma unroll
    for (int mt = 0; mt < 2; ++mt)
        #pragma unroll
        for (int nt = 0; nt < 2; ++nt)
            #pragma unroll
            for (int r = 0; r < 4; ++r) {
                int p = p0 + mt * 16 + quad * 4 + r;
                int n = nb + nt * 16 + col;
                float c0 = first ? 0.f : cfg[p * 128 + n];
                cv[mt][nt][r] = c0;
                zo[mt][nt][r] = c0;
                Zbuf[0][(mt * 16 + quad * 4 + r) * 136 + n] = f2bf(c0);
            }
    __syncthreads();

    f32x4 acc[2][2];
    auto matmul = [&](const unsigned short* Zr) {
        short8_t af[2][4];
        #pragma unroll
        for (int mt = 0; mt < 2; ++mt)
            #pragma unroll
            for (int s = 0; s < 4; ++s)
                af[mt][s] = *(const short8_t*)&Zr[(mt * 16 + col) * 136 + s * 32 + quad * 8];
        #pragma unroll
        for (int mt = 0; mt < 2; ++mt)
            #pragma unroll
            for (int nt = 0; nt < 2; ++nt)
                acc[mt][nt] = (f32x4){0.f, 0.f, 0.f, 0.f};
        #pragma unroll
        for (int s = 0; s < 4; ++s)
            #pragma unroll
            for (int mt = 0; mt < 2; ++mt)
                #pragma unroll
                for (int nt = 0; nt < 2; ++nt)
                    acc[mt][nt] = __builtin_amdgcn_mfma_f32_16x16x32_bf16(
                        af[mt][s], xf[nt][s], acc[mt][nt], 0, 0, 0);
    };

    float tm = 1.0f;
    int cur = 0;
    #pragma unroll 1
    for (int it = 0; it < 14; ++it) {          // FISTA iters 1..14 (write z)
        matmul(Zbuf[cur]);
        float tnn = 0.5f * (1.0f + sqrtf(1.0f + 4.0f * tm * tm));
        float fm = (tm - 1.0f) / tnn;
        tm = tnn;
        unsigned short* Zw = Zbuf[cur ^ 1];
        #pragma unroll
        for (int mt = 0; mt < 2; ++mt)
            #pragma unroll
            for (int nt = 0; nt < 2; ++nt)
                #pragma unroll
                for (int r = 0; r < 4; ++r) {
                    float df = qv[mt][nt][r] - acc[mt][nt][r];
                    float u = fmaf(mu, df, zo[mt][nt][r]);
                    float cl = fminf(fmaxf(u, -LAM), LAM);
                    float cn = u - cl;
                    float d = cn - cv[mt][nt][r];
                    float zn = fmaf(fm, d, cn);
                    cv[mt][nt][r] = cn;
                    zo[mt][nt][r] = zn;
                    Zw[(mt * 16 + quad * 4 + r) * 136 + nb + nt * 16 + col] = f2bh(zn);
                }
        __syncthreads();
        cur ^= 1;
    }
    {   // FISTA iter 15: compute c15; stage c15 (z15 never consumed)
        matmul(Zbuf[cur]);
        unsigned short* Zw = Zbuf[cur ^ 1];
        #pragma unroll
        for (int mt = 0; mt < 2; ++mt)
            #pragma unroll
            for (int nt = 0; nt < 2; ++nt)
                #pragma unroll
                for (int r = 0; r < 4; ++r) {
                    float df = qv[mt][nt][r] - acc[mt][nt][r];
                    float u = fmaf(mu, df, zo[mt][nt][r]);
                    float cl = fminf(fmaxf(u, -LAM), LAM);
                    float cn = u - cl;
                    cv[mt][nt][r] = cn;
                    Zw[(mt * 16 + quad * 4 + r) * 136 + nb + nt * 16 + col] = f2bh(cn);
                }
        __syncthreads();
        cur ^= 1;
    }
    {   // final differentiable step: cf = prox(c15 + mu*(q - X@c15)); stage cf bf16
        matmul(Zbuf[cur]);
        unsigned short* Zw = Zbuf[cur ^ 1];
        #pragma unroll
        for (int mt = 0; mt < 2; ++mt)
            #pragma unroll
            for (int nt = 0; nt < 2; ++nt)
                #pragma unroll
                for (int r = 0; r < 4; ++r) {
                    float df = qv[mt][nt][r] - acc[mt][nt][r];
                    float u = fmaf(mu, df, cv[mt][nt][r]);
                    float cl = fminf(fmaxf(u, -LAM), LAM);
                    float cf = u - cl;
                    cfg[(p0 + mt * 16 + quad * 4 + r) * 128 + nb + nt * 16 + col] = cf;
                    Zw[(mt * 16 + quad * 4 + r) * 136 + nb + nt * 16 + col] = f2bh(cf);
                }
        __syncthreads();
        cur ^= 1;
    }

    // ---- pred tail: pred[32][144] = cf @ atoms_n + pm. j-tiles split 3/2/2/2. ----
    {
        int jt0 = (w == 0) ? 0 : (2 * w + 1);
        int jtn = (w == 0) ? 3 : 2;
        const unsigned short* Zr = Zbuf[cur];
        short8_t af[2][4];
        #pragma unroll
        for (int mt = 0; mt < 2; ++mt)
            #pragma unroll
            for (int s = 0; s < 4; ++s)
                af[mt][s] = *(const short8_t*)&Zr[(mt * 16 + col) * 136 + s * 32 + quad * 8];
        f32x4 accp[2][3];
        #pragma unroll
        for (int mt = 0; mt < 2; ++mt)
            #pragma unroll
            for (int ji = 0; ji < 3; ++ji)
                accp[mt][ji] = (f32x4){0.f, 0.f, 0.f, 0.f};
        #pragma unroll
        for (int ji = 0; ji < 3; ++ji) {
            if (ji < jtn) {
                int jt = jt0 + ji;
                short8_t bf4[4];
                #pragma unroll
                for (int s = 0; s < 4; ++s)
                    bf4[s] = *(const short8_t*)&ANTB[(jt * 16 + col) * 128 + s * 32 + quad * 8];
                #pragma unroll
                for (int mt = 0; mt < 2; ++mt)
                    #pragma unroll
                    for (int s = 0; s < 4; ++s)
                        accp[mt][ji] = __builtin_amdgcn_mfma_f32_16x16x32_bf16(
                            af[mt][s], bf4[s], accp[mt][ji], 0, 0, 0);
            }
        }
        #pragma unroll
        for (int mt = 0; mt < 2; ++mt)
            #pragma unroll
            for (int r = 0; r < 4; ++r) {
                int p = p0 + mt * 16 + quad * 4 + r;
                float pmv = pm[p];
                #pragma unroll
                for (int ji = 0; ji < 3; ++ji)
                    if (ji < jtn)
                        pred[p * 144 + (jt0 + ji) * 16 + col] = accp[mt][ji][r] + pmv;
            }
    }
}

// ---- fold via LDS staging: block = (output row i, batch b); coalesced pred reads. ----
__global__ __launch_bounds__(256) void k_fold(const float* y, const float* beta_p,
                                              const float* pred, float* goal,
                                              float* out, int write_out) {
    __shared__ float P[12 * 832];              // 39,936 B
    int i = blockIdx.x, b = blockIdx.y;
    int t = threadIdx.x;
    for (int di = 0; di < 12; ++di) {
        int pi = i - di;
        if ((unsigned)pi >= 64u) continue;     // uniform per block
        int base = (b << 12) + (pi << 6);
        #pragma unroll
        for (int it = 0; it < 3; ++it) {
            int e = t + it * 256;              // < 768 = 64 pj * 12 dj
            int pj = e / 12, dj = e - pj * 12;
            P[di * 832 + pj * 13 + dj] = pred[(base + pj) * AA + di * 12 + dj];
        }
    }
    __syncthreads();
    if (t >= 75) return;
    int j = t;
    float S = 0.f;
    for (int di = 0; di < 12; ++di) {
        if ((unsigned)(i - di) >= 64u) continue;
        const float* Pd = &P[di * 832];
        #pragma unroll
        for (int dj = 0; dj < 12; ++dj) {
            int pj = j - dj;
            if ((unsigned)pj >= 64u) continue;
            S += Pd[pj * 13 + dj];
        }
    }
    int ci = min(i, 11) - max(i - 63, 0) + 1;
    int cj = min(j, 11) - max(j - 63, 0) + 1;
    float beta = fmaxf(beta_p[0], 0.0f);
    int idx = i * 75 + j;
    float yv = y[b * 5625 + idx];
    float g = (yv + beta * S) / (1.0f + beta * (float)(ci * cj));
    goal[b * 5625 + idx] = g;
    if (write_out) out[b * 5625 + idx] = g;
}

extern "C" void kernel_launch(void* const* d_in, const int* in_sizes, int n_in,
                              void* d_out, int out_size, void* d_ws, size_t ws_size,
                              hipStream_t stream) {
    const float* y     = (const float*)d_in[0];
    const float* atoms = (const float*)d_in[1];
    const float* beta  = (const float*)d_in[2];
    const float* mu    = (const float*)d_in[3];
    float* out = (float*)d_out;
    float* ws = (float*)d_ws;

    k_norm<<<1, 256, 0, stream>>>(atoms, ws);
    k_gram<<<16, 256, 0, stream>>>(ws);
    for (int j = 0; j < 8; ++j) {           // G^(2^8) via trace-normalized squaring
        const float* IN = ws + (j == 0 ? OFS_G : ((j & 1) ? OFS_S0 : OFS_S1));
        float* OUT = ws + ((j & 1) ? OFS_S1 : OFS_S0);
        k_square<<<64, 256, 0, stream>>>(IN, OUT, ws + OFS_SC + j, ws + OFS_SC + j + 1);
    }
    k_rayleigh<<<1, 128, 0, stream>>>(ws + OFS_S1, ws + OFS_G, mu, ws + OFS_SC);
    k_finalize<<<392, 256, 0, stream>>>(ws, y);     // X + bf16 weights + goal + patchmean

    for (int u = 0; u < 2; ++u) {
        k_fista<<<1024, 256, 0, stream>>>(ws + OFS_X, ws + OFS_GOAL,
                                          (const unsigned short*)(ws + OFS_ATB),
                                          (const unsigned short*)(ws + OFS_ANTB),
                                          ws + OFS_PM, ws + OFS_CF, ws + OFS_PRED,
                                          mu, u == 0 ? 1 : 0);
        k_fold<<<dim3(75, 8), 256, 0, stream>>>(y, beta, ws + OFS_PRED,
                                                ws + OFS_GOAL, out, u == 1 ? 1 : 0);
    }
}

// Round 9
// 291.365 us; speedup vs baseline: 2.7922x; 1.0015x over previous
//
#include <hip/hip_runtime.h>
#include <stdint.h>

// Problem constants
#define AA 144          // ATOM*ATOM
#define LAM 0.1f

// ---- workspace layout (float offsets) ----
#define OFS_SC    0            // 64 scalars: [0..15]=traces, [16]=scX, [17]=scA
#define OFS_AF1   64           // 128*144 row-normalized zero-mean atoms
#define OFS_AF1T  18496        // 144*128 transposed
#define OFS_G     36928        // 128*128 gram
#define OFS_S0    53312        // squaring ping; later ATB (bf16 atoms, [128][160] u16)
#define OFS_S1    69696        // squaring pong; later ANTBP (bf16 atomsT, n-permuted, [144][128] u16)
#define OFS_X     86080        // XPB: bf16 X, k-permuted, [128][128] u16
#define OFS_PM    139328       // 32768 patch means
#define OFS_GOAL  172096       // 45056 goal (f32)
#define OFS_CF    4411456      // 32768*128
#define OFS_PRED  8605760      // 32768*144
#define OFS_ATB   OFS_S0
#define OFS_ANTB  OFS_S1

// Contraction-dim permutation: real n = 32g + 16v + u  <->  stored ks = 32g + 2u + v.
// A (Z in LDS) and B (XPB / ANTBP) both use stored order -> dot products unchanged.

typedef __attribute__((ext_vector_type(8))) short short8_t;
typedef __attribute__((ext_vector_type(4))) float f32x4;

__device__ __forceinline__ unsigned short f2bf(float f) {      // RNE
    union { float f; uint32_t u; } x; x.f = f;
    uint32_t u = x.u;
    return (unsigned short)((u + 0x7FFFu + ((u >> 16) & 1u)) >> 16);
}
// pack two f32 -> packed bf16 pair (a->low, b->high), round-half-up, 3 VALU ops
__device__ __forceinline__ uint32_t pack_bf(float a, float b) {
    union { float f; uint32_t u; } xa, xb; xa.f = a; xb.f = b;
    return __builtin_amdgcn_perm(xb.u + 0x8000u, xa.u + 0x8000u, 0x07060302u);
}

// ---- setup: per-atom zero-mean unit-norm rows -> Af1, Af1T; init trace slots ----
__global__ __launch_bounds__(256) void k_norm(const float* atoms, float* ws) {
    int t = threadIdx.x;
    if (t >= 128 && t < 144) ws[OFS_SC + (t - 128)] = (t == 128) ? 128.0f : 0.0f;
    if (t < 128) {
        const float* ap = atoms + t * AA;
        float s = 0.f;
        for (int k = 0; k < AA; ++k) s += ap[k];
        float mean = s * (1.0f / 144.0f);
        float ss = 0.f;
        for (int k = 0; k < AA; ++k) { float a = ap[k] - mean; ss = fmaf(a, a, ss); }
        float rn = 1.0f / sqrtf(ss);
        for (int k = 0; k < AA; ++k) {
            float a = (ap[k] - mean) * rn;
            ws[OFS_AF1  + t * AA + k] = a;
            ws[OFS_AF1T + k * 128 + t] = a;
        }
    }
}

// ---- G = Af1 @ Af1^T ----
__global__ __launch_bounds__(256) void k_gram(float* ws) {
    __shared__ float Ai[8 * AA];
    int t = threadIdx.x;
    int i0 = blockIdx.x * 8;
    for (int e = t; e < 8 * AA; e += 256) Ai[e] = ws[OFS_AF1 + i0 * AA + e];
    __syncthreads();
    int ti = t >> 5, tj = t & 31;
    float a0 = 0, a1 = 0, a2 = 0, a3 = 0;
    for (int k = 0; k < AA; ++k) {
        float a = Ai[ti * AA + k];
        float4 bv = *(const float4*)&ws[OFS_AF1T + k * 128 + tj * 4];
        a0 = fmaf(a, bv.x, a0); a1 = fmaf(a, bv.y, a1);
        a2 = fmaf(a, bv.z, a2); a3 = fmaf(a, bv.w, a3);
    }
    *(float4*)&ws[OFS_G + (i0 + ti) * 128 + tj * 4] = make_float4(a0, a1, a2, a3);
}

// ---- OUT = (IN/trace_in)^2, IN symmetric: C[r][c] = dot(row r, row c).
//      Both operands contiguous float4 — no LDS, no transpose. ----
__global__ __launch_bounds__(256) void k_square(const float* IN, float* OUT,
                                                const float* tr_in, float* tr_out) {
    int t = threadIdx.x;
    int r = blockIdx.x * 2 + (t >> 7), c = t & 127;
    float s = tr_in[0];
    float inv2 = 1.0f / (s * s);
    const float4* Ra = (const float4*)(IN + r * 128);
    const float4* Rb = (const float4*)(IN + c * 128);
    float acc = 0.f;
    #pragma unroll 8
    for (int k = 0; k < 32; ++k) {
        float4 a = Ra[k], b = Rb[k];
        acc = fmaf(a.x, b.x, acc); acc = fmaf(a.y, b.y, acc);
        acc = fmaf(a.z, b.z, acc); acc = fmaf(a.w, b.w, acc);
    }
    acc *= inv2;
    OUT[r * 128 + c] = acc;
    if (c == r) atomicAdd(tr_out, acc);
}

// ---- Rayleigh quotient on P ~ G^256: v = P*ones; lam = v'Gv / v'v ----
__global__ __launch_bounds__(128) void k_rayleigh(const float* P, const float* G,
                                                  const float* mu_p, float* sc) {
    __shared__ float v[128];
    __shared__ float red[256];
    int t = threadIdx.x;
    float s = 0.f;
    for (int k = 0; k < 128; ++k) s += P[t * 128 + k];
    v[t] = s;
    __syncthreads();
    float w = 0.f;
    for (int k = 0; k < 128; ++k) w = fmaf(G[t * 128 + k], v[k], w);
    red[t] = v[t] * w;
    red[128 + t] = v[t] * v[t];
    __syncthreads();
    for (int off = 64; off > 0; off >>= 1) {
        if (t < off) { red[t] += red[t + off]; red[128 + t] += red[128 + t + off]; }
        __syncthreads();
    }
    if (t == 0) {
        float lam = red[0] / red[128];               // sigma^2 = lammax(G)
        float mu = fmaxf(mu_p[0], 0.0f);
        sc[16] = 1.0f / (lam * mu);                  // X scale
        sc[17] = 1.0f / (sqrtf(lam) * sqrtf(mu));    // atom scale
    }
}

// ---- finalize: XPB (bf16, k-permuted) ; ATB ; ANTBP (n-permuted) ; goal ; pm ----
__global__ __launch_bounds__(256) void k_finalize(float* ws, const float* y) {
    int idx = blockIdx.x * 256 + threadIdx.x;       // grid 392 -> 100352
    float scX = ws[OFS_SC + 16], scA = ws[OFS_SC + 17];
    if (idx < 16384) {
        int n = idx >> 7, ks = idx & 127;
        int g = ks >> 5, rem = ks & 31, u = rem >> 1, v = rem & 1;
        int k = g * 32 + v * 16 + u;                // pi^-1(ks)
        ((unsigned short*)(ws + OFS_X))[idx] = f2bf(ws[OFS_G + n * 128 + k] * scX);
    } else if (idx < 36864) {
        int e = idx - 16384;                        // ATB [n=128][k=160] zero-pad
        int n = e / 160, k = e - n * 160;
        float v = (k < 144) ? ws[OFS_AF1 + n * 144 + k] * scA : 0.f;
        ((unsigned short*)(ws + OFS_ATB))[e] = f2bf(v);
    } else if (idx < 55296) {
        int e = idx - 36864;                        // ANTBP [jpix=144][ks=128]
        int jp = e >> 7, ks = e & 127;
        int g = ks >> 5, rem = ks & 31, u = rem >> 1, v = rem & 1;
        int n = g * 32 + v * 16 + u;                // pi^-1(ks)
        ((unsigned short*)(ws + OFS_ANTB))[e] = f2bf(ws[OFS_AF1 + n * 144 + jp] * scA);
    } else {
        int e = idx - 55296;                        // < 45056
        if (e < 45000) ws[OFS_GOAL + e] = y[e];
        if (e < 32768) {
            int b = e >> 12, pi = (e >> 6) & 63, pj = e & 63;
            const float* yb = y + b * 5625;
            float s = 0.f;
            for (int di = 0; di < 12; ++di) {
                const float* row = yb + (pi + di) * 75 + pj;
                #pragma unroll
                for (int dj = 0; dj < 12; ++dj) s += row[dj];
            }
            ws[OFS_PM + e] = s * (1.0f / 144.0f);
        }
    }
}

// ---- fused megakernel: q (im2col MFMA) + FISTA(15)+1 + pred.
//      Z stored column-interleaved (pi): epilogue writes are paired b32.
//      LDS: gls 2112 + Atile 10752 + Z dbuf 17408 = 30272 B. ----
__global__ __launch_bounds__(256) void k_fista(const unsigned short* XPB, const float* goal,
                                               const unsigned short* ATB,
                                               const unsigned short* ANTBP,
                                               const float* pm, float* cfg, float* pred,
                                               const float* mu_p, int first) {
    __shared__ float gls[12 * 44];
    __shared__ unsigned short Atile[32 * 168];
    __shared__ unsigned short Zbuf[2][32 * 136];
    int t = threadIdx.x;
    int lane = t & 63, w = t >> 6;
    int col = lane & 15, quad = lane >> 4;
    int nb = w * 32;
    int blk = blockIdx.x;
    int b = blk >> 7, pi = (blk >> 1) & 63, h = blk & 1;
    int p0 = blk * 32;
    float mu = fmaxf(mu_p[0], 0.0f);

    // ---- stage goal slice (12 x 44, zero-pad past col 74) ----
    for (int e = t; e < 528; e += 256) {
        int r = e / 44, cc = e - r * 44;
        int gc = h * 32 + cc;
        gls[e] = (gc < 75) ? goal[b * 5625 + (pi + r) * 75 + gc] : 0.f;
    }
    __syncthreads();
    // ---- im2col A-tile 32 x 160 bf16, pair-packed b32 writes ----
    {
        uint32_t* A32 = (uint32_t*)Atile;          // row stride 84 u32
        #pragma unroll
        for (int i = 0; i < 10; ++i) {
            int pe = t + i * 256;                  // < 2560 = 32m * 80 pairs
            int m = pe / 80, q32 = pe - m * 80;
            int kk = q32 * 2;
            float v0 = 0.f, v1 = 0.f;
            if (kk < 144) {
                int di = kk / 12, dj = kk - di * 12;
                v0 = gls[di * 44 + m + dj];
                int k1 = kk + 1;
                int di1 = k1 / 12, dj1 = k1 - di1 * 12;
                v1 = gls[di1 * 44 + m + dj1];
            }
            A32[m * 84 + q32] = pack_bf(v0, v1);
        }
    }
    __syncthreads();

    // ---- q-matmul: qv = im2col @ atoms^T (natural k-order), C/D layout ----
    float qv[2][2][4];
    {
        short8_t bfq[2][5];
        #pragma unroll
        for (int nt = 0; nt < 2; ++nt)
            #pragma unroll
            for (int s = 0; s < 5; ++s)
                bfq[nt][s] = *(const short8_t*)&ATB[(nb + nt * 16 + col) * 160 + s * 32 + quad * 8];
        #pragma unroll
        for (int mt = 0; mt < 2; ++mt) {
            short8_t af[5];
            #pragma unroll
            for (int s = 0; s < 5; ++s)
                af[s] = *(const short8_t*)&Atile[(mt * 16 + col) * 168 + s * 32 + quad * 8];
            f32x4 acc0 = (f32x4){0.f, 0.f, 0.f, 0.f};
            f32x4 acc1 = (f32x4){0.f, 0.f, 0.f, 0.f};
            #pragma unroll
            for (int s = 0; s < 5; ++s) {
                acc0 = __builtin_amdgcn_mfma_f32_16x16x32_bf16(af[s], bfq[0][s], acc0, 0, 0, 0);
                acc1 = __builtin_amdgcn_mfma_f32_16x16x32_bf16(af[s], bfq[1][s], acc1, 0, 0, 0);
            }
            #pragma unroll
            for (int r = 0; r < 4; ++r) { qv[mt][0][r] = acc0[r]; qv[mt][1][r] = acc1[r]; }
        }
    }

    // ---- X B-fragments: contiguous b128 from pre-permuted bf16 XPB ----
    short8_t xf[2][4];
    #pragma unroll
    for (int nt = 0; nt < 2; ++nt)
        #pragma unroll
        for (int s = 0; s < 4; ++s)
            xf[nt][s] = *(const short8_t*)&XPB[(nb + nt * 16 + col) * 128 + s * 32 + quad * 8];

    // ---- c0 / z0 init, seed Z (paired b32, interleaved cols) ----
    uint32_t* Z32w = (uint32_t*)Zbuf[0];           // row stride 68 u32
    float cv[2][2][4], zo[2][2][4];
    #pragma unroll
    for (int mt = 0; mt < 2; ++mt)
        #pragma unroll
        for (int r = 0; r < 4; ++r) {
            int row = mt * 16 + quad * 4 + r;
            int p = p0 + row;
            float c0 = 0.f, c1 = 0.f;
            if (!first) {
                c0 = cfg[p * 128 + nb + col];
                c1 = cfg[p * 128 + nb + 16 + col];
            }
            cv[mt][0][r] = c0; cv[mt][1][r] = c1;
            zo[mt][0][r] = c0; zo[mt][1][r] = c1;
            Z32w[row * 68 + 16 * w + col] = pack_bf(c0, c1);
        }
    __syncthreads();

    f32x4 acc[2][2];
    auto matmul = [&](const unsigned short* Zr) {
        short8_t af[2][4];
        #pragma unroll
        for (int mt = 0; mt < 2; ++mt)
            #pragma unroll
            for (int s = 0; s < 4; ++s)
                af[mt][s] = *(const short8_t*)&Zr[(mt * 16 + col) * 136 + s * 32 + quad * 8];
        #pragma unroll
        for (int mt = 0; mt < 2; ++mt)
            #pragma unroll
            for (int nt = 0; nt < 2; ++nt)
                acc[mt][nt] = (f32x4){0.f, 0.f, 0.f, 0.f};
        #pragma unroll
        for (int s = 0; s < 4; ++s)
            #pragma unroll
            for (int mt = 0; mt < 2; ++mt)
                #pragma unroll
                for (int nt = 0; nt < 2; ++nt)
                    acc[mt][nt] = __builtin_amdgcn_mfma_f32_16x16x32_bf16(
                        af[mt][s], xf[nt][s], acc[mt][nt], 0, 0, 0);
    };

    float tm = 1.0f;
    int cur = 0;
    #pragma unroll 1
    for (int it = 0; it < 14; ++it) {          // FISTA iters 1..14 (write z)
        matmul(Zbuf[cur]);
        float tnn = 0.5f * (1.0f + sqrtf(1.0f + 4.0f * tm * tm));
        float fm = (tm - 1.0f) / tnn;
        tm = tnn;
        uint32_t* Zw = (uint32_t*)Zbuf[cur ^ 1];
        #pragma unroll
        for (int mt = 0; mt < 2; ++mt)
            #pragma unroll
            for (int r = 0; r < 4; ++r) {
                float zn2[2];
                #pragma unroll
                for (int nt = 0; nt < 2; ++nt) {
                    float df = qv[mt][nt][r] - acc[mt][nt][r];
                    float u = fmaf(mu, df, zo[mt][nt][r]);
                    float cl = fminf(fmaxf(u, -LAM), LAM);
                    float cn = u - cl;
                    float d = cn - cv[mt][nt][r];
                    float zn = fmaf(fm, d, cn);
                    cv[mt][nt][r] = cn;
                    zo[mt][nt][r] = zn;
                    zn2[nt] = zn;
                }
                Zw[(mt * 16 + quad * 4 + r) * 68 + 16 * w + col] = pack_bf(zn2[0], zn2[1]);
            }
        __syncthreads();
        cur ^= 1;
    }
    {   // FISTA iter 15: compute c15; stage c15 (z15 never consumed)
        matmul(Zbuf[cur]);
        uint32_t* Zw = (uint32_t*)Zbuf[cur ^ 1];
        #pragma unroll
        for (int mt = 0; mt < 2; ++mt)
            #pragma unroll
            for (int r = 0; r < 4; ++r) {
                float cn2[2];
                #pragma unroll
                for (int nt = 0; nt < 2; ++nt) {
                    float df = qv[mt][nt][r] - acc[mt][nt][r];
                    float u = fmaf(mu, df, zo[mt][nt][r]);
                    float cl = fminf(fmaxf(u, -LAM), LAM);
                    float cn = u - cl;
                    cv[mt][nt][r] = cn;
                    cn2[nt] = cn;
                }
                Zw[(mt * 16 + quad * 4 + r) * 68 + 16 * w + col] = pack_bf(cn2[0], cn2[1]);
            }
        __syncthreads();
        cur ^= 1;
    }
    {   // final differentiable step: cf = prox(c15 + mu*(q - X@c15)); stage cf
        matmul(Zbuf[cur]);
        uint32_t* Zw = (uint32_t*)Zbuf[cur ^ 1];
        #pragma unroll
        for (int mt = 0; mt < 2; ++mt)
            #pragma unroll
            for (int r = 0; r < 4; ++r) {
                int row = mt * 16 + quad * 4 + r;
                float cf2[2];
                #pragma unroll
                for (int nt = 0; nt < 2; ++nt) {
                    float df = qv[mt][nt][r] - acc[mt][nt][r];
                    float u = fmaf(mu, df, cv[mt][nt][r]);
                    float cl = fminf(fmaxf(u, -LAM), LAM);
                    float cf = u - cl;
                    cfg[(p0 + row) * 128 + nb + nt * 16 + col] = cf;
                    cf2[nt] = cf;
                }
                Zw[row * 68 + 16 * w + col] = pack_bf(cf2[0], cf2[1]);
            }
        __syncthreads();
        cur ^= 1;
    }

    // ---- pred tail: pred[32][144] = cf @ atoms_n + pm (B pre-permuted ANTBP) ----
    {
        int jt0 = (w == 0) ? 0 : (2 * w + 1);
        int jtn = (w == 0) ? 3 : 2;
        const unsigned short* Zr = Zbuf[cur];
        short8_t af[2][4];
        #pragma unroll
        for (int mt = 0; mt < 2; ++mt)
            #pragma unroll
            for (int s = 0; s < 4; ++s)
                af[mt][s] = *(const short8_t*)&Zr[(mt * 16 + col) * 136 + s * 32 + quad * 8];
        f32x4 accp[2][3];
        #pragma unroll
        for (int mt = 0; mt < 2; ++mt)
            #pragma unroll
            for (int ji = 0; ji < 3; ++ji)
                accp[mt][ji] = (f32x4){0.f, 0.f, 0.f, 0.f};
        #pragma unroll
        for (int ji = 0; ji < 3; ++ji) {
            if (ji < jtn) {
                int jt = jt0 + ji;
                short8_t bf4[4];
                #pragma unroll
                for (int s = 0; s < 4; ++s)
                    bf4[s] = *(const short8_t*)&ANTBP[(jt * 16 + col) * 128 + s * 32 + quad * 8];
                #pragma unroll
                for (int mt = 0; mt < 2; ++mt)
                    #pragma unroll
                    for (int s = 0; s < 4; ++s)
                        accp[mt][ji] = __builtin_amdgcn_mfma_f32_16x16x32_bf16(
                            af[mt][s], bf4[s], accp[mt][ji], 0, 0, 0);
            }
        }
        #pragma unroll
        for (int mt = 0; mt < 2; ++mt)
            #pragma unroll
            for (int r = 0; r < 4; ++r) {
                int p = p0 + mt * 16 + quad * 4 + r;
                float pmv = pm[p];
                #pragma unroll
                for (int ji = 0; ji < 3; ++ji)
                    if (ji < jtn)
                        pred[p * 144 + (jt0 + ji) * 16 + col] = accp[mt][ji][r] + pmv;
            }
    }
}

// ---- fold via LDS staging: block = (output row i, batch b); coalesced pred reads. ----
__global__ __launch_bounds__(256) void k_fold(const float* y, const float* beta_p,
                                              const float* pred, float* goal,
                                              float* out, int write_out) {
    __shared__ float P[12 * 832];              // 39,936 B
    int i = blockIdx.x, b = blockIdx.y;
    int t = threadIdx.x;
    for (int di = 0; di < 12; ++di) {
        int pi = i - di;
        if ((unsigned)pi >= 64u) continue;     // uniform per block
        int base = (b << 12) + (pi << 6);
        #pragma unroll
        for (int it = 0; it < 3; ++it) {
            int e = t + it * 256;              // < 768 = 64 pj * 12 dj
            int pj = e / 12, dj = e - pj * 12;
            P[di * 832 + pj * 13 + dj] = pred[(base + pj) * AA + di * 12 + dj];
        }
    }
    __syncthreads();
    if (t >= 75) return;
    int j = t;
    float S = 0.f;
    for (int di = 0; di < 12; ++di) {
        if ((unsigned)(i - di) >= 64u) continue;
        const float* Pd = &P[di * 832];
        #pragma unroll
        for (int dj = 0; dj < 12; ++dj) {
            int pj = j - dj;
            if ((unsigned)pj >= 64u) continue;
            S += Pd[pj * 13 + dj];
        }
    }
    int ci = min(i, 11) - max(i - 63, 0) + 1;
    int cj = min(j, 11) - max(j - 63, 0) + 1;
    float beta = fmaxf(beta_p[0], 0.0f);
    int idx = i * 75 + j;
    float yv = y[b * 5625 + idx];
    float g = (yv + beta * S) / (1.0f + beta * (float)(ci * cj));
    goal[b * 5625 + idx] = g;
    if (write_out) out[b * 5625 + idx] = g;
}

extern "C" void kernel_launch(void* const* d_in, const int* in_sizes, int n_in,
                              void* d_out, int out_size, void* d_ws, size_t ws_size,
                              hipStream_t stream) {
    const float* y     = (const float*)d_in[0];
    const float* atoms = (const float*)d_in[1];
    const float* beta  = (const float*)d_in[2];
    const float* mu    = (const float*)d_in[3];
    float* out = (float*)d_out;
    float* ws = (float*)d_ws;

    k_norm<<<1, 256, 0, stream>>>(atoms, ws);
    k_gram<<<16, 256, 0, stream>>>(ws);
    for (int j = 0; j < 8; ++j) {           // G^(2^8) via trace-normalized squaring
        const float* IN = ws + (j == 0 ? OFS_G : ((j & 1) ? OFS_S0 : OFS_S1));
        float* OUT = ws + ((j & 1) ? OFS_S1 : OFS_S0);
        k_square<<<64, 256, 0, stream>>>(IN, OUT, ws + OFS_SC + j, ws + OFS_SC + j + 1);
    }
    k_rayleigh<<<1, 128, 0, stream>>>(ws + OFS_S1, ws + OFS_G, mu, ws + OFS_SC);
    k_finalize<<<392, 256, 0, stream>>>(ws, y);     // XPB + ATB + ANTBP + goal + pm

    for (int u = 0; u < 2; ++u) {
        k_fista<<<1024, 256, 0, stream>>>((const unsigned short*)(ws + OFS_X),
                                          ws + OFS_GOAL,
                                          (const unsigned short*)(ws + OFS_ATB),
                                          (const unsigned short*)(ws + OFS_ANTB),
                                          ws + OFS_PM, ws + OFS_CF, ws + OFS_PRED,
                                          mu, u == 0 ? 1 : 0);
        k_fold<<<dim3(75, 8), 256, 0, stream>>>(y, beta, ws + OFS_PRED,
                                                ws + OFS_GOAL, out, u == 1 ? 1 : 0);
    }
}

// Round 10
// 264.500 us; speedup vs baseline: 3.0758x; 1.1016x over previous
//
#include <hip/hip_runtime.h>
#include <stdint.h>

// Problem constants
#define AA 144          // ATOM*ATOM
#define LAM 0.1f

// ---- workspace layout (float offsets) ----
#define OFS_SC    0            // 64 scalars: [16]=scX, [17]=scA
#define OFS_AF1   64           // 128*144 row-normalized zero-mean atoms
#define OFS_AF1T  18496        // 144*128 transposed
#define OFS_G     36928        // 128*128 gram (f32)
#define OFS_S0    53312        // ATB (bf16 atoms, [128][160] u16)
#define OFS_S1    69696        // ANTBP (bf16 atomsT, n-permuted, [144][128] u16)
#define OFS_X     86080        // XPB: bf16 X, k-permuted, [128][128] u16
#define OFS_PM    139328       // 32768 patch means
#define OFS_GOAL  172096       // 45056 goal (f32)
#define OFS_CF    4411456      // 32768*128
#define OFS_PRED  8605760      // 32768*144
#define OFS_ATB   OFS_S0
#define OFS_ANTB  OFS_S1

// Contraction-dim permutation: real n = 32g + 16v + u  <->  stored ks = 32g + 2u + v.
// A and B sides both use stored order -> dot products unchanged.

typedef __attribute__((ext_vector_type(8))) short short8_t;
typedef __attribute__((ext_vector_type(4))) float f32x4;

__device__ __forceinline__ unsigned short f2bf(float f) {      // RNE
    union { float f; uint32_t u; } x; x.f = f;
    uint32_t u = x.u;
    return (unsigned short)((u + 0x7FFFu + ((u >> 16) & 1u)) >> 16);
}
__device__ __forceinline__ float bf2f(unsigned short u) {
    union { float f; uint32_t i; } x; x.i = ((uint32_t)u) << 16; return x.f;
}
// pack two f32 -> packed bf16 pair (a->low, b->high), round-half-up
__device__ __forceinline__ uint32_t pack_bf(float a, float b) {
    union { float f; uint32_t u; } xa, xb; xa.f = a; xb.f = b;
    return __builtin_amdgcn_perm(xb.u + 0x8000u, xa.u + 0x8000u, 0x07060302u);
}

// ---- setup: per-atom zero-mean unit-norm rows -> Af1, Af1T ----
__global__ __launch_bounds__(256) void k_norm(const float* atoms, float* ws) {
    int t = threadIdx.x;
    if (t < 128) {
        const float* ap = atoms + t * AA;
        float s = 0.f;
        for (int k = 0; k < AA; ++k) s += ap[k];
        float mean = s * (1.0f / 144.0f);
        float ss = 0.f;
        for (int k = 0; k < AA; ++k) { float a = ap[k] - mean; ss = fmaf(a, a, ss); }
        float rn = 1.0f / sqrtf(ss);
        for (int k = 0; k < AA; ++k) {
            float a = (ap[k] - mean) * rn;
            ws[OFS_AF1  + t * AA + k] = a;
            ws[OFS_AF1T + k * 128 + t] = a;
        }
    }
}

// ---- G = Af1 @ Af1^T ----
__global__ __launch_bounds__(256) void k_gram(float* ws) {
    __shared__ float Ai[8 * AA];
    int t = threadIdx.x;
    int i0 = blockIdx.x * 8;
    for (int e = t; e < 8 * AA; e += 256) Ai[e] = ws[OFS_AF1 + i0 * AA + e];
    __syncthreads();
    int ti = t >> 5, tj = t & 31;
    float a0 = 0, a1 = 0, a2 = 0, a3 = 0;
    for (int k = 0; k < AA; ++k) {
        float a = Ai[ti * AA + k];
        float4 bv = *(const float4*)&ws[OFS_AF1T + k * 128 + tj * 4];
        a0 = fmaf(a, bv.x, a0); a1 = fmaf(a, bv.y, a1);
        a2 = fmaf(a, bv.z, a2); a3 = fmaf(a, bv.w, a3);
    }
    *(float4*)&ws[OFS_G + (i0 + ti) * 128 + tj * 4] = make_float4(a0, a1, a2, a3);
}

// ---- fused spectral norm: 8x trace-normalized bf16 MFMA squarings (one block,
//      ping-pong LDS) + f32 Rayleigh on G. Scale of P cancels in the quotient;
//      bf16 eigvec noise enters Rayleigh only quadratically. ----
#define PSTR 136
__global__ __launch_bounds__(256) void k_power(const float* G, const float* mu_p, float* sc) {
    __shared__ unsigned short Pb[2][128 * PSTR];
    __shared__ float tr_arr[10];
    __shared__ float v[128];
    __shared__ float red[256];
    int t = threadIdx.x;
    int lane = t & 63, w = t >> 6;
    int col = lane & 15, quad = lane >> 4;
    if (t < 10) tr_arr[t] = (t == 0) ? 128.0f : 0.f;
    // load G -> bf16, column-permuted storage
    for (int i = 0; i < 64; ++i) {
        int e = t + i * 256;                  // 16384
        int m = e >> 7, ks = e & 127;
        int g = ks >> 5, rem = ks & 31, u = rem >> 1, vv = rem & 1;
        int k = g * 32 + vv * 16 + u;
        Pb[0][m * PSTR + ks] = f2bf(G[m * 128 + k]);
    }
    __syncthreads();
    int cur = 0;
    #pragma unroll 1
    for (int j = 0; j < 8; ++j) {
        float trn = tr_arr[j];
        float inv2 = 1.0f / (trn * trn);
        const unsigned short* S = Pb[cur];
        uint32_t* D32 = (uint32_t*)Pb[cur ^ 1];     // row stride 68 u32
        short8_t bf[2][4];
        #pragma unroll
        for (int nt = 0; nt < 2; ++nt)
            #pragma unroll
            for (int s = 0; s < 4; ++s)
                bf[nt][s] = *(const short8_t*)&S[(32 * w + nt * 16 + col) * PSTR + s * 32 + quad * 8];
        int n0 = 32 * w + col, n1 = n0 + 16;
        #pragma unroll
        for (int mt = 0; mt < 8; ++mt) {
            short8_t af[4];
            #pragma unroll
            for (int s = 0; s < 4; ++s)
                af[s] = *(const short8_t*)&S[(mt * 16 + col) * PSTR + s * 32 + quad * 8];
            f32x4 a0 = (f32x4){0.f, 0.f, 0.f, 0.f};
            f32x4 a1 = (f32x4){0.f, 0.f, 0.f, 0.f};
            #pragma unroll
            for (int s = 0; s < 4; ++s) {
                a0 = __builtin_amdgcn_mfma_f32_16x16x32_bf16(af[s], bf[0][s], a0, 0, 0, 0);
                a1 = __builtin_amdgcn_mfma_f32_16x16x32_bf16(af[s], bf[1][s], a1, 0, 0, 0);
            }
            #pragma unroll
            for (int r = 0; r < 4; ++r) {
                float x0 = a0[r] * inv2, x1 = a1[r] * inv2;
                int row = mt * 16 + quad * 4 + r;
                D32[row * 68 + 16 * w + col] = pack_bf(x0, x1);
                if (row == n0) atomicAdd(&tr_arr[j + 1], x0);
                if (row == n1) atomicAdd(&tr_arr[j + 1], x1);
            }
        }
        __syncthreads();
        cur ^= 1;
    }
    // v = P * ones (row sums; column permutation irrelevant)
    if (t < 128) {
        const unsigned short* S = Pb[cur];
        float s = 0.f;
        for (int k = 0; k < 128; ++k) s += bf2f(S[t * PSTR + k]);
        v[t] = s;
    }
    __syncthreads();
    if (t < 128) {
        float wv = 0.f;
        for (int k = 0; k < 128; ++k) wv = fmaf(G[t * 128 + k], v[k], wv);
        red[t] = v[t] * wv;
        red[128 + t] = v[t] * v[t];
    }
    __syncthreads();
    for (int off = 64; off > 0; off >>= 1) {
        if (t < off) { red[t] += red[t + off]; red[128 + t] += red[128 + t + off]; }
        __syncthreads();
    }
    if (t == 0) {
        float lam = red[0] / red[128];               // sigma^2 = lammax(G)
        float mu = fmaxf(mu_p[0], 0.0f);
        sc[16] = 1.0f / (lam * mu);                  // X scale
        sc[17] = 1.0f / (sqrtf(lam) * sqrtf(mu));    // atom scale
    }
}

// ---- finalize: XPB (bf16, k-permuted) ; ATB ; ANTBP (n-permuted) ; goal ; pm ----
__global__ __launch_bounds__(256) void k_finalize(float* ws, const float* y) {
    int idx = blockIdx.x * 256 + threadIdx.x;       // grid 392 -> 100352
    float scX = ws[OFS_SC + 16], scA = ws[OFS_SC + 17];
    if (idx < 16384) {
        int n = idx >> 7, ks = idx & 127;
        int g = ks >> 5, rem = ks & 31, u = rem >> 1, v = rem & 1;
        int k = g * 32 + v * 16 + u;                // pi^-1(ks)
        ((unsigned short*)(ws + OFS_X))[idx] = f2bf(ws[OFS_G + n * 128 + k] * scX);
    } else if (idx < 36864) {
        int e = idx - 16384;                        // ATB [n=128][k=160] zero-pad
        int n = e / 160, k = e - n * 160;
        float v = (k < 144) ? ws[OFS_AF1 + n * 144 + k] * scA : 0.f;
        ((unsigned short*)(ws + OFS_ATB))[e] = f2bf(v);
    } else if (idx < 55296) {
        int e = idx - 36864;                        // ANTBP [jpix=144][ks=128]
        int jp = e >> 7, ks = e & 127;
        int g = ks >> 5, rem = ks & 31, u = rem >> 1, v = rem & 1;
        int n = g * 32 + v * 16 + u;                // pi^-1(ks)
        ((unsigned short*)(ws + OFS_ANTB))[e] = f2bf(ws[OFS_AF1 + n * 144 + jp] * scA);
    } else {
        int e = idx - 55296;                        // < 45056
        if (e < 45000) ws[OFS_GOAL + e] = y[e];
        if (e < 32768) {
            int b = e >> 12, pi = (e >> 6) & 63, pj = e & 63;
            const float* yb = y + b * 5625;
            float s = 0.f;
            for (int di = 0; di < 12; ++di) {
                const float* row = yb + (pi + di) * 75 + pj;
                #pragma unroll
                for (int dj = 0; dj < 12; ++dj) s += row[dj];
            }
            ws[OFS_PM + e] = s * (1.0f / 144.0f);
        }
    }
}

// ---- fused megakernel: q (im2col MFMA) + FISTA(15)+1 + pred.
//      Z stored column-interleaved: epilogue writes are paired b32. ----
__global__ __launch_bounds__(256) void k_fista(const unsigned short* XPB, const float* goal,
                                               const unsigned short* ATB,
                                               const unsigned short* ANTBP,
                                               const float* pm, float* cfg, float* pred,
                                               const float* mu_p, int first, int write_cf) {
    __shared__ float gls[12 * 44];
    __shared__ unsigned short Atile[32 * 168];
    __shared__ unsigned short Zbuf[2][32 * 136];
    int t = threadIdx.x;
    int lane = t & 63, w = t >> 6;
    int col = lane & 15, quad = lane >> 4;
    int nb = w * 32;
    int blk = blockIdx.x;
    int b = blk >> 7, pi = (blk >> 1) & 63, h = blk & 1;
    int p0 = blk * 32;
    float mu = fmaxf(mu_p[0], 0.0f);

    // ---- stage goal slice (12 x 44, zero-pad past col 74) ----
    for (int e = t; e < 528; e += 256) {
        int r = e / 44, cc = e - r * 44;
        int gc = h * 32 + cc;
        gls[e] = (gc < 75) ? goal[b * 5625 + (pi + r) * 75 + gc] : 0.f;
    }
    __syncthreads();
    // ---- im2col A-tile 32 x 160 bf16, pair-packed b32 writes ----
    {
        uint32_t* A32 = (uint32_t*)Atile;          // row stride 84 u32
        #pragma unroll
        for (int i = 0; i < 10; ++i) {
            int pe = t + i * 256;                  // < 2560 = 32m * 80 pairs
            int m = pe / 80, q32 = pe - m * 80;
            int kk = q32 * 2;
            float v0 = 0.f, v1 = 0.f;
            if (kk < 144) {
                int di = kk / 12, dj = kk - di * 12;
                v0 = gls[di * 44 + m + dj];
                int k1 = kk + 1;
                int di1 = k1 / 12, dj1 = k1 - di1 * 12;
                v1 = gls[di1 * 44 + m + dj1];
            }
            A32[m * 84 + q32] = pack_bf(v0, v1);
        }
    }
    __syncthreads();

    // ---- q-matmul: qv = im2col @ atoms^T (natural k-order), C/D layout ----
    float qv[2][2][4];
    {
        short8_t bfq[2][5];
        #pragma unroll
        for (int nt = 0; nt < 2; ++nt)
            #pragma unroll
            for (int s = 0; s < 5; ++s)
                bfq[nt][s] = *(const short8_t*)&ATB[(nb + nt * 16 + col) * 160 + s * 32 + quad * 8];
        #pragma unroll
        for (int mt = 0; mt < 2; ++mt) {
            short8_t af[5];
            #pragma unroll
            for (int s = 0; s < 5; ++s)
                af[s] = *(const short8_t*)&Atile[(mt * 16 + col) * 168 + s * 32 + quad * 8];
            f32x4 acc0 = (f32x4){0.f, 0.f, 0.f, 0.f};
            f32x4 acc1 = (f32x4){0.f, 0.f, 0.f, 0.f};
            #pragma unroll
            for (int s = 0; s < 5; ++s) {
                acc0 = __builtin_amdgcn_mfma_f32_16x16x32_bf16(af[s], bfq[0][s], acc0, 0, 0, 0);
                acc1 = __builtin_amdgcn_mfma_f32_16x16x32_bf16(af[s], bfq[1][s], acc1, 0, 0, 0);
            }
            #pragma unroll
            for (int r = 0; r < 4; ++r) { qv[mt][0][r] = acc0[r]; qv[mt][1][r] = acc1[r]; }
        }
    }

    // ---- X B-fragments: contiguous b128 from pre-permuted bf16 XPB ----
    short8_t xf[2][4];
    #pragma unroll
    for (int nt = 0; nt < 2; ++nt)
        #pragma unroll
        for (int s = 0; s < 4; ++s)
            xf[nt][s] = *(const short8_t*)&XPB[(nb + nt * 16 + col) * 128 + s * 32 + quad * 8];

    // ---- c0 / z0 init, seed Z (paired b32, interleaved cols) ----
    uint32_t* Z32w = (uint32_t*)Zbuf[0];           // row stride 68 u32
    float cv[2][2][4], zo[2][2][4];
    #pragma unroll
    for (int mt = 0; mt < 2; ++mt)
        #pragma unroll
        for (int r = 0; r < 4; ++r) {
            int row = mt * 16 + quad * 4 + r;
            int p = p0 + row;
            float c0 = 0.f, c1 = 0.f;
            if (!first) {
                c0 = cfg[p * 128 + nb + col];
                c1 = cfg[p * 128 + nb + 16 + col];
            }
            cv[mt][0][r] = c0; cv[mt][1][r] = c1;
            zo[mt][0][r] = c0; zo[mt][1][r] = c1;
            Z32w[row * 68 + 16 * w + col] = pack_bf(c0, c1);
        }
    __syncthreads();

    f32x4 acc[2][2];
    auto matmul = [&](const unsigned short* Zr) {
        short8_t af[2][4];
        #pragma unroll
        for (int mt = 0; mt < 2; ++mt)
            #pragma unroll
            for (int s = 0; s < 4; ++s)
                af[mt][s] = *(const short8_t*)&Zr[(mt * 16 + col) * 136 + s * 32 + quad * 8];
        #pragma unroll
        for (int mt = 0; mt < 2; ++mt)
            #pragma unroll
            for (int nt = 0; nt < 2; ++nt)
                acc[mt][nt] = (f32x4){0.f, 0.f, 0.f, 0.f};
        #pragma unroll
        for (int s = 0; s < 4; ++s)
            #pragma unroll
            for (int mt = 0; mt < 2; ++mt)
                #pragma unroll
                for (int nt = 0; nt < 2; ++nt)
                    acc[mt][nt] = __builtin_amdgcn_mfma_f32_16x16x32_bf16(
                        af[mt][s], xf[nt][s], acc[mt][nt], 0, 0, 0);
    };

    float tm = 1.0f;
    int cur = 0;
    #pragma unroll 1
    for (int it = 0; it < 14; ++it) {          // FISTA iters 1..14 (write z)
        matmul(Zbuf[cur]);
        float tnn = 0.5f * (1.0f + sqrtf(1.0f + 4.0f * tm * tm));
        float fm = (tm - 1.0f) / tnn;
        tm = tnn;
        uint32_t* Zw = (uint32_t*)Zbuf[cur ^ 1];
        #pragma unroll
        for (int mt = 0; mt < 2; ++mt)
            #pragma unroll
            for (int r = 0; r < 4; ++r) {
                float zn2[2];
                #pragma unroll
                for (int nt = 0; nt < 2; ++nt) {
                    float df = qv[mt][nt][r] - acc[mt][nt][r];
                    float u = fmaf(mu, df, zo[mt][nt][r]);
                    float cl = fminf(fmaxf(u, -LAM), LAM);
                    float cn = u - cl;
                    float d = cn - cv[mt][nt][r];
                    float zn = fmaf(fm, d, cn);
                    cv[mt][nt][r] = cn;
                    zo[mt][nt][r] = zn;
                    zn2[nt] = zn;
                }
                Zw[(mt * 16 + quad * 4 + r) * 68 + 16 * w + col] = pack_bf(zn2[0], zn2[1]);
            }
        __syncthreads();
        cur ^= 1;
    }
    {   // FISTA iter 15: compute c15; stage c15 (z15 never consumed)
        matmul(Zbuf[cur]);
        uint32_t* Zw = (uint32_t*)Zbuf[cur ^ 1];
        #pragma unroll
        for (int mt = 0; mt < 2; ++mt)
            #pragma unroll
            for (int r = 0; r < 4; ++r) {
                float cn2[2];
                #pragma unroll
                for (int nt = 0; nt < 2; ++nt) {
                    float df = qv[mt][nt][r] - acc[mt][nt][r];
                    float u = fmaf(mu, df, zo[mt][nt][r]);
                    float cl = fminf(fmaxf(u, -LAM), LAM);
                    float cn = u - cl;
                    cv[mt][nt][r] = cn;
                    cn2[nt] = cn;
                }
                Zw[(mt * 16 + quad * 4 + r) * 68 + 16 * w + col] = pack_bf(cn2[0], cn2[1]);
            }
        __syncthreads();
        cur ^= 1;
    }
    {   // final differentiable step: cf = prox(c15 + mu*(q - X@c15)); stage cf
        matmul(Zbuf[cur]);
        uint32_t* Zw = (uint32_t*)Zbuf[cur ^ 1];
        #pragma unroll
        for (int mt = 0; mt < 2; ++mt)
            #pragma unroll
            for (int r = 0; r < 4; ++r) {
                int row = mt * 16 + quad * 4 + r;
                float cf2[2];
                #pragma unroll
                for (int nt = 0; nt < 2; ++nt) {
                    float df = qv[mt][nt][r] - acc[mt][nt][r];
                    float u = fmaf(mu, df, cv[mt][nt][r]);
                    float cl = fminf(fmaxf(u, -LAM), LAM);
                    float cf = u - cl;
                    if (write_cf)
                        cfg[(p0 + row) * 128 + nb + nt * 16 + col] = cf;
                    cf2[nt] = cf;
                }
                Zw[row * 68 + 16 * w + col] = pack_bf(cf2[0], cf2[1]);
            }
        __syncthreads();
        cur ^= 1;
    }

    // ---- pred tail: pred[32][144] = cf @ atoms_n + pm (B pre-permuted ANTBP) ----
    {
        int jt0 = (w == 0) ? 0 : (2 * w + 1);
        int jtn = (w == 0) ? 3 : 2;
        const unsigned short* Zr = Zbuf[cur];
        short8_t af[2][4];
        #pragma unroll
        for (int mt = 0; mt < 2; ++mt)
            #pragma unroll
            for (int s = 0; s < 4; ++s)
                af[mt][s] = *(const short8_t*)&Zr[(mt * 16 + col) * 136 + s * 32 + quad * 8];
        f32x4 accp[2][3];
        #pragma unroll
        for (int mt = 0; mt < 2; ++mt)
            #pragma unroll
            for (int ji = 0; ji < 3; ++ji)
                accp[mt][ji] = (f32x4){0.f, 0.f, 0.f, 0.f};
        #pragma unroll
        for (int ji = 0; ji < 3; ++ji) {
            if (ji < jtn) {
                int jt = jt0 + ji;
                short8_t bf4[4];
                #pragma unroll
                for (int s = 0; s < 4; ++s)
                    bf4[s] = *(const short8_t*)&ANTBP[(jt * 16 + col) * 128 + s * 32 + quad * 8];
                #pragma unroll
                for (int mt = 0; mt < 2; ++mt)
                    #pragma unroll
                    for (int s = 0; s < 4; ++s)
                        accp[mt][ji] = __builtin_amdgcn_mfma_f32_16x16x32_bf16(
                            af[mt][s], bf4[s], accp[mt][ji], 0, 0, 0);
            }
        }
        #pragma unroll
        for (int mt = 0; mt < 2; ++mt)
            #pragma unroll
            for (int r = 0; r < 4; ++r) {
                int p = p0 + mt * 16 + quad * 4 + r;
                float pmv = pm[p];
                #pragma unroll
                for (int ji = 0; ji < 3; ++ji)
                    if (ji < jtn)
                        pred[p * 144 + (jt0 + ji) * 16 + col] = accp[mt][ji][r] + pmv;
            }
    }
}

// ---- fold via LDS staging: block = (output row i, batch b); coalesced pred reads. ----
__global__ __launch_bounds__(256) void k_fold(const float* y, const float* beta_p,
                                              const float* pred, float* goal,
                                              float* out, int write_out) {
    __shared__ float P[12 * 832];              // 39,936 B
    int i = blockIdx.x, b = blockIdx.y;
    int t = threadIdx.x;
    for (int di = 0; di < 12; ++di) {
        int pi = i - di;
        if ((unsigned)pi >= 64u) continue;     // uniform per block
        int base = (b << 12) + (pi << 6);
        #pragma unroll
        for (int it = 0; it < 3; ++it) {
            int e = t + it * 256;              // < 768 = 64 pj * 12 dj
            int pj = e / 12, dj = e - pj * 12;
            P[di * 832 + pj * 13 + dj] = pred[(base + pj) * AA + di * 12 + dj];
        }
    }
    __syncthreads();
    if (t >= 75) return;
    int j = t;
    float S = 0.f;
    for (int di = 0; di < 12; ++di) {
        if ((unsigned)(i - di) >= 64u) continue;
        const float* Pd = &P[di * 832];
        #pragma unroll
        for (int dj = 0; dj < 12; ++dj) {
            int pj = j - dj;
            if ((unsigned)pj >= 64u) continue;
            S += Pd[pj * 13 + dj];
        }
    }
    int ci = min(i, 11) - max(i - 63, 0) + 1;
    int cj = min(j, 11) - max(j - 63, 0) + 1;
    float beta = fmaxf(beta_p[0], 0.0f);
    int idx = i * 75 + j;
    float yv = y[b * 5625 + idx];
    float g = (yv + beta * S) / (1.0f + beta * (float)(ci * cj));
    if (write_out) out[b * 5625 + idx] = g;
    else           goal[b * 5625 + idx] = g;
}

extern "C" void kernel_launch(void* const* d_in, const int* in_sizes, int n_in,
                              void* d_out, int out_size, void* d_ws, size_t ws_size,
                              hipStream_t stream) {
    const float* y     = (const float*)d_in[0];
    const float* atoms = (const float*)d_in[1];
    const float* beta  = (const float*)d_in[2];
    const float* mu    = (const float*)d_in[3];
    float* out = (float*)d_out;
    float* ws = (float*)d_ws;

    k_norm<<<1, 256, 0, stream>>>(atoms, ws);
    k_gram<<<16, 256, 0, stream>>>(ws);
    k_power<<<1, 256, 0, stream>>>(ws + OFS_G, mu, ws + OFS_SC);
    k_finalize<<<392, 256, 0, stream>>>(ws, y);     // XPB + ATB + ANTBP + goal + pm

    for (int u = 0; u < 2; ++u) {
        k_fista<<<1024, 256, 0, stream>>>((const unsigned short*)(ws + OFS_X),
                                          ws + OFS_GOAL,
                                          (const unsigned short*)(ws + OFS_ATB),
                                          (const unsigned short*)(ws + OFS_ANTB),
                                          ws + OFS_PM, ws + OFS_CF, ws + OFS_PRED,
                                          mu, u == 0 ? 1 : 0, u == 0 ? 1 : 0);
        k_fold<<<dim3(75, 8), 256, 0, stream>>>(y, beta, ws + OFS_PRED,
                                                ws + OFS_GOAL, out, u == 1 ? 1 : 0);
    }
}